// Round 6
// baseline (780.326 us; speedup 1.0000x reference)
//
#include <hip/hip_runtime.h>
#include <hip/hip_bf16.h>

// ---------------------------------------------------------------------------
// Attention block: B=2 S=2048 D=4096 H=32 KV=8 HD=128 (GQA N_REP=4, causal)
// Pipeline: cvt -> GEMM8-splitK(qkv, bf16 partials) -> RoPE/sum/scatter
//           -> flash-attn -> GEMM8(out)
// ---------------------------------------------------------------------------

typedef __attribute__((ext_vector_type(8))) short  s8v;   // 8 x bf16 (4 VGPR)
typedef __attribute__((ext_vector_type(4))) short  s4v;   // 4 x bf16 (2 VGPR)
typedef __attribute__((ext_vector_type(4))) float  f4v;
typedef __attribute__((ext_vector_type(2))) float  f2v;
typedef __attribute__((ext_vector_type(2))) unsigned int u2v;
typedef __attribute__((ext_vector_type(4))) unsigned int u4v;

typedef __attribute__((address_space(3))) void lds_void;
typedef __attribute__((address_space(1))) void g_void;

#define GLDS16(gp, lp) __builtin_amdgcn_global_load_lds((g_void*)(gp), (lds_void*)(lp), 16, 0, 0)

__device__ __forceinline__ unsigned short f2b(float f) {  // f32 -> bf16 RNE
  unsigned u = __builtin_bit_cast(unsigned, f);
  u += 0x7fffu + ((u >> 16) & 1u);
  return (unsigned short)(u >> 16);
}
__device__ __forceinline__ unsigned pk2(float a, float b) {
  return (unsigned)f2b(a) | ((unsigned)f2b(b) << 16);
}
__device__ __forceinline__ float b2f(unsigned short h) {
  return __builtin_bit_cast(float, (unsigned)h << 16);
}

// inline-asm MFMAs (volatile; s_nop guards at every MFMA->VALU read-back)
__device__ __forceinline__ void mfma32(f4v& d, s8v a, s8v b) {
  asm volatile("v_mfma_f32_16x16x32_bf16 %0, %1, %2, %0" : "+v"(d) : "v"(a), "v"(b));
}
__device__ __forceinline__ void mfma16(f4v& d, s4v a, s4v b) {
  asm volatile("v_mfma_f32_16x16x16_bf16 %0, %1, %2, %0" : "+v"(d) : "v"(a), "v"(b));
}
__device__ __forceinline__ s4v tr_read(const char* p, int imm) {
  s4v r;
  asm volatile("ds_read_b64_tr_b16 %0, %1 offset:%2"
               : "=v"(r) : "v"((lds_void*)p), "n"(imm));
  return r;
}

// ---------------------------------------------------------------------------
// f32 -> bf16 convert
// ---------------------------------------------------------------------------
__global__ __launch_bounds__(256) void cvt_bf16(const float* __restrict__ s,
                                                unsigned short* __restrict__ d, int n4) {
  const int i = blockIdx.x * 256 + threadIdx.x;
  if (i >= n4) return;
  f4v v = *(const f4v*)(s + (size_t)i * 4);
  u2v r;
  r.x = pk2(v[0], v[1]);
  r.y = pk2(v[2], v[3]);
  *(u2v*)(d + (size_t)i * 4) = r;
}

// ---------------------------------------------------------------------------
// 8-phase GEMM, C = A[M][Ks] * B[N][Ks]^T over K range [kOff, kOff+Klen).
// 256x256 tile, BK=64, 512 thr = 8 waves (2M x 4N), 128 KiB LDS double-buffer.
// (unchanged from round 5 — see that round's race analysis)
// ---------------------------------------------------------------------------
#define BAR      asm volatile("s_barrier" ::: "memory")
#define WLGKM    do { asm volatile("s_waitcnt lgkmcnt(0)" ::: "memory"); \
                      __builtin_amdgcn_sched_barrier(0); } while (0)
#define WVM4     do { asm volatile("s_waitcnt vmcnt(4)" ::: "memory"); \
                      __builtin_amdgcn_sched_barrier(0); } while (0)

template <int OUTB>
__global__ __launch_bounds__(512, 2) void gemm_bt8(const unsigned short* __restrict__ A,
                                                   const unsigned short* __restrict__ Bp,
                                                   void* __restrict__ Cout,
                                                   int M, int N, int Ks, int Klen,
                                                   int nTiles) {
  __shared__ __align__(16) char smem[131072];
  const int tid = threadIdx.x, lane = tid & 63, wv = tid >> 6;
  const int qi = lane & 15, g = lane >> 4;
  const int wm = wv >> 2, wn = wv & 3;

  const int nwg = gridDim.x, cpx = nwg >> 3;
  const int id = blockIdx.x;
  const int swz = (id & 7) * cpx + (id >> 3);
  const int half = swz / nTiles;
  const int tile = swz - half * nTiles;
  const int kOff = half * Klen;
  const int MT = M >> 8;
  const int m0 = (tile % MT) * 256, n0 = (tile / MT) * 256;
  const int NT = Klen >> 6;

  const int srowo = wv * 8 + (lane >> 3);
  const int scole = ((lane & 7) ^ (lane >> 3)) << 3;
  const size_t rA = (size_t)(m0 + srowo) * Ks + kOff + scole;
  const size_t rB = (size_t)(n0 + srowo) * Ks + kOff + scole;
  char* sdA = smem + wv * 1024;
  char* sdB = smem + 32768 + wv * 1024;

#define STG_A(D, H, KT) do { \
    GLDS16(A + rA + (size_t)((H)*128) * Ks + (size_t)(KT)*64,      sdA + (D)*65536 + (H)*16384); \
    GLDS16(A + rA + (size_t)((H)*128 + 64) * Ks + (size_t)(KT)*64, sdA + (D)*65536 + (H)*16384 + 8192); } while (0)
#define STG_B(D, H, KT) do { \
    GLDS16(Bp + rB + (size_t)((H)*128) * Ks + (size_t)(KT)*64,      sdB + (D)*65536 + (H)*16384); \
    GLDS16(Bp + rB + (size_t)((H)*128 + 64) * Ks + (size_t)(KT)*64, sdB + (D)*65536 + (H)*16384 + 8192); } while (0)

  const int sw = (qi & 7) << 4;
  const char* frA = smem + (wm * 128 + qi) * 128;
  const char* frB = smem + 32768 + (wn * 64 + qi) * 128;

#define RDA4(D, F0) do { _Pragma("unroll") for (int f_ = 0; f_ < 4; ++f_) \
    _Pragma("unroll") for (int k_ = 0; k_ < 2; ++k_) \
      a[(F0) + f_][k_] = *(const s8v*)(frA + (D)*65536 + ((F0) + f_) * 2048 + (((k_ << 6) + (g << 4)) ^ sw)); } while (0)
#define RDB2(D, N0) do { _Pragma("unroll") for (int n_ = 0; n_ < 2; ++n_) \
    _Pragma("unroll") for (int k_ = 0; k_ < 2; ++k_) \
      b[(N0) + n_][k_] = *(const s8v*)(frB + (D)*65536 + ((N0) + n_) * 2048 + (((k_ << 6) + (g << 4)) ^ sw)); } while (0)
#define MQUAD(F0, N0) do { __builtin_amdgcn_s_setprio(1); \
    _Pragma("unroll") for (int f_ = 0; f_ < 4; ++f_) \
    _Pragma("unroll") for (int n_ = 0; n_ < 2; ++n_) \
    _Pragma("unroll") for (int k_ = 0; k_ < 2; ++k_) \
      mfma32(acc[(F0) + f_][(N0) + n_], a[(F0) + f_][k_], b[(N0) + n_][k_]); \
    __builtin_amdgcn_s_setprio(0); } while (0)

  f4v acc[8][4];
#pragma unroll
  for (int i = 0; i < 8; ++i)
#pragma unroll
    for (int j = 0; j < 4; ++j) acc[i][j] = (f4v)0.0f;

  STG_A(0, 0, 0); STG_A(0, 1, 0);
  STG_B(0, 0, 0); STG_B(0, 1, 0);
  STG_A(1, 0, 1); STG_A(1, 1, 1);
  WVM4;
  BAR;

  s8v a[8][2], b[4][2];
#pragma unroll 1
  for (int it = 0; it < NT / 2; ++it) {
    const int t = 2 * it;
    const int k2 = (t + 2 < NT) ? t + 2 : NT - 1;
    const int k3 = (t + 3 < NT) ? t + 3 : NT - 1;
    RDA4(0, 0); RDB2(0, 0);
    STG_B(1, 0, t + 1);
    BAR; WLGKM; MQUAD(0, 0); BAR;
    RDA4(0, 4);
    STG_B(1, 1, t + 1);
    BAR; WLGKM; MQUAD(4, 0); BAR;
    RDB2(0, 2);
    STG_A(0, 0, k2);
    BAR; WLGKM; MQUAD(0, 2); BAR;
    STG_A(0, 1, k2);
    BAR; WLGKM; MQUAD(4, 2);
    WVM4;
    BAR;
    RDA4(1, 0); RDB2(1, 0);
    STG_B(0, 0, k2);
    BAR; WLGKM; MQUAD(0, 0); BAR;
    RDA4(1, 4);
    STG_B(0, 1, k2);
    BAR; WLGKM; MQUAD(4, 0); BAR;
    RDB2(1, 2);
    STG_A(1, 0, k3);
    BAR; WLGKM; MQUAD(0, 2); BAR;
    STG_A(1, 1, k3);
    BAR; WLGKM; MQUAD(4, 2);
    WVM4;
    BAR;
  }

  asm volatile("s_waitcnt vmcnt(0)" ::: "memory");
  asm volatile("s_nop 7\n\ts_nop 7" ::: "memory");
  const int r4 = g * 4;
  if (OUTB) {
    unsigned short* Cb = (unsigned short*)Cout + (size_t)half * M * N;
#pragma unroll
    for (int fm = 0; fm < 8; ++fm)
#pragma unroll
      for (int fn = 0; fn < 4; ++fn)
#pragma unroll
        for (int r = 0; r < 4; ++r)
          Cb[(size_t)(m0 + wm * 128 + fm * 16 + r4 + r) * N + (n0 + wn * 64 + fn * 16 + qi)] =
              f2b(acc[fm][fn][r]);
  } else {
    float* Cf = (float*)Cout;
#pragma unroll
    for (int fm = 0; fm < 8; ++fm)
#pragma unroll
      for (int fn = 0; fn < 4; ++fn)
#pragma unroll
        for (int r = 0; r < 4; ++r)
          Cf[(size_t)(m0 + wm * 128 + fm * 16 + r4 + r) * N + (n0 + wn * 64 + fn * 16 + qi)] =
              acc[fm][fn][r];
  }
}

// ---------------------------------------------------------------------------
// RoPE + splitK-sum + scatter (unchanged from round 5)
// ---------------------------------------------------------------------------
__global__ __launch_bounds__(256) void rope_scatter(
    const unsigned short* __restrict__ qkvp, const float* __restrict__ fr,
    const float* __restrict__ fi,
    unsigned short* __restrict__ qb, unsigned short* __restrict__ kb,
    unsigned short* __restrict__ vbuf, float* __restrict__ xk, float* __restrict__ xv) {
  const int idx = blockIdx.x * 256 + threadIdx.x;
  const int token = idx / 3072;
  const int col2  = (idx - token * 3072) * 2;
  const int pos   = token & 2047;
  const unsigned u1 = *(const unsigned*)(qkvp + (size_t)token * 6144 + col2);
  const unsigned u2 = *(const unsigned*)(qkvp + 25165824u + (size_t)token * 6144 + col2);
  float v0 = b2f((unsigned short)u1) + b2f((unsigned short)u2);
  float v1 = b2f((unsigned short)(u1 >> 16)) + b2f((unsigned short)(u2 >> 16));
  if (col2 < 4096) {
    const int j = (col2 & 127) >> 1;
    const float cr = fr[pos * 64 + j], ci = fi[pos * 64 + j];
    const float a = v0 * cr - ci * v1;
    const float o = v0 * ci + v1 * cr;
    *(unsigned*)(qb + (size_t)token * 4096 + col2) = pk2(a, o);
  } else if (col2 < 5120) {
    const int lc = col2 - 4096;
    const int j = (lc & 127) >> 1;
    const float cr = fr[pos * 64 + j], ci = fi[pos * 64 + j];
    const float a = v0 * cr - ci * v1;
    const float o = v0 * ci + v1 * cr;
    *(unsigned*)(kb + (size_t)token * 1024 + lc) = pk2(a, o);
    f2v w; w.x = a; w.y = o;
    *(f2v*)(xk + (size_t)token * 1024 + lc) = w;
  } else {
    const int lc = col2 - 5120;
    *(unsigned*)(vbuf + (size_t)token * 1024 + lc) = pk2(v0, v1);
    f2v w; w.x = v0; w.y = v1;
    *(f2v*)(xv + (size_t)token * 1024 + lc) = w;
  }
}

// ---------------------------------------------------------------------------
// Causal GQA flash attention. Round-6 changes vs round-5:
//  * staging remap: row = wv*4+(lane&3), chunk=(lane>>2)&15 -> V ds_write
//    spans all 32 banks per lane-quarter (was 8-way conflict), K-write <=2-way
//  * K/V LDS double-buffer (2x16K each): ONE barrier per tile
//  * PV tr_read 1-deep pipeline: first batch issued before softmax; counted
//    s_waitcnt lgkmcnt(8) between batches (FIFO semantics), sched_barrier
// ---------------------------------------------------------------------------
#define SCL_LOG2 0.12751744f   // (1/sqrt(128)) * log2(e)

__global__ __launch_bounds__(512, 4) void attn_fwd(
    const unsigned short* __restrict__ qb, const unsigned short* __restrict__ kb,
    const unsigned short* __restrict__ vb, unsigned short* __restrict__ ao) {
  __shared__ __align__(16) char smem[65536];   // K[2]:0..32K  V[2]:32K..64K; epi reuse
  const int tid = threadIdx.x, lane = tid & 63, wv = tid >> 6;
  const int qi = lane & 15, g = lane >> 4;
  const int qtb = 15 - blockIdx.x;            // long blocks launch first
  const int h = blockIdx.y, b = blockIdx.z;
  const int kvh = h >> 2;
  const int q0 = qtb * 128;
  const int qrow = q0 + wv * 16 + qi;

  s8v qf[4];
  {
    const unsigned short* qp = qb + (size_t)(b * 2048 + qrow) * 4096 + h * 128 + g * 8;
#pragma unroll
    for (int c = 0; c < 4; ++c) qf[c] = *(const s8v*)(qp + c * 32);
  }

  f4v oacc[8];
#pragma unroll
  for (int i = 0; i < 8; ++i) oacc[i] = (f4v)0.0f;
  float m_run = -3.0e38f, l_run = 0.0f;

  // staging geometry (remapped): per pass j, this thread owns key row
  // srow + 32j, d-chunk sc (8 elems). Wave covers 4 keys x full 128-d.
  const int srow = wv * 4 + (lane & 3);
  const int sc   = (lane >> 2) & 15;
  const unsigned short* kg = kb + (size_t)b * 2048 * 1024 + kvh * 128 + sc * 8;
  const unsigned short* vg = vb + (size_t)b * 2048 * 1024 + kvh * 128 + sc * 8;

  int kwo[2], vwo[2];
#pragma unroll
  for (int j = 0; j < 2; ++j) {
    const int row = srow + j * 32;
    kwo[j] = row * 256 + ((sc * 16) ^ ((row & 7) << 4));
    vwo[j] = ((row >> 4) * 4 + ((row >> 2) & 3)) * 1024 + (sc >> 1) * 128 +
             (row & 3) * 32 + (sc & 1) * 16;
  }

  const int ntiles = 2 * qtb + 2;
  const int my_qmax = q0 + wv * 16 + 15;
  const int wq_lo = q0 + wv * 16;

  s8v kreg0, kreg1, vreg0, vreg1;             // T14 prefetch registers
  kreg0 = *(const s8v*)(kg + (size_t)srow * 1024);
  kreg1 = *(const s8v*)(kg + (size_t)(srow + 32) * 1024);
  vreg0 = *(const s8v*)(vg + (size_t)srow * 1024);
  vreg1 = *(const s8v*)(vg + (size_t)(srow + 32) * 1024);

  for (int t = 0; t < ntiles; ++t) {
    char* Kb = smem + (t & 1) * 16384;
    char* Vb = smem + 32768 + (t & 1) * 16384;
    *(s8v*)(Kb + kwo[0]) = kreg0; *(s8v*)(Kb + kwo[1]) = kreg1;
    *(s8v*)(Vb + vwo[0]) = vreg0; *(s8v*)(Vb + vwo[1]) = vreg1;
    if (t + 1 < ntiles) {                     // issue next tile's loads now
      const size_t base = (size_t)(t + 1) * 64 * 1024;
      kreg0 = *(const s8v*)(kg + base + (size_t)srow * 1024);
      kreg1 = *(const s8v*)(kg + base + (size_t)(srow + 32) * 1024);
      vreg0 = *(const s8v*)(vg + base + (size_t)srow * 1024);
      vreg1 = *(const s8v*)(vg + base + (size_t)(srow + 32) * 1024);
    }
    __syncthreads();                          // single barrier per tile (dbuf)
    const int k0 = t * 64;
    if (k0 <= my_qmax) {
      // ---- S^T[key][q] = K * Q^T
      f4v s4k[4];
#pragma unroll
      for (int kt = 0; kt < 4; ++kt) s4k[kt] = (f4v)0.0f;
      __builtin_amdgcn_s_setprio(1);
#pragma unroll
      for (int kt = 0; kt < 4; ++kt) {
        const char* kbase = Kb + (kt * 16 + qi) * 256;
        const int sw = (qi & 7) << 4;
#pragma unroll
        for (int c = 0; c < 4; ++c) {
          s8v kf = *(const s8v*)(kbase + ((c * 64 + g * 16) ^ sw));
          mfma32(s4k[kt], kf, qf[c]);
        }
      }
      __builtin_amdgcn_s_setprio(0);
      asm volatile("s_nop 7\n\ts_nop 7"
        : "+v"(s4k[0]), "+v"(s4k[1]), "+v"(s4k[2]), "+v"(s4k[3]));

      // ---- PV batch 0 tr_reads issued NOW; latency hides under softmax
      s4v vfA[8], vfB[8];
      {
        const char* tb0 = Vb + g * 1024 + qi * 8;
#pragma unroll
        for (int dt = 0; dt < 8; ++dt) vfA[dt] = tr_read(tb0, dt * 128);
      }

      // ---- scale (+mask only on partial tiles); per-lane running max
      float tm = -3.0e38f;
      if (k0 + 64 <= wq_lo) {
#pragma unroll
        for (int kt = 0; kt < 4; ++kt)
#pragma unroll
          for (int r = 0; r < 4; ++r) {
            s4k[kt][r] *= SCL_LOG2;
            tm = fmaxf(tm, s4k[kt][r]);
          }
      } else {
#pragma unroll
        for (int kt = 0; kt < 4; ++kt)
#pragma unroll
          for (int r = 0; r < 4; ++r) {
            const int keyg = k0 + kt * 16 + g * 4 + r;
            s4k[kt][r] = (keyg <= qrow) ? s4k[kt][r] * SCL_LOG2 : -3.0e38f;
            tm = fmaxf(tm, s4k[kt][r]);
          }
      }
      tm = fmaxf(tm, __shfl_xor(tm, 16));
      tm = fmaxf(tm, __shfl_xor(tm, 32));

      // ---- T13 defer-max
      if (!__all(tm - m_run <= 8.0f)) {
        const float m_new = fmaxf(m_run, tm);
        const float al = exp2f(m_run - m_new);
#pragma unroll
        for (int i = 0; i < 8; ++i) oacc[i] *= al;
        l_run *= al;
        m_run = m_new;
      }
      float ps = 0.0f;
#pragma unroll
      for (int kt = 0; kt < 4; ++kt)
#pragma unroll
        for (int r = 0; r < 4; ++r) {
          s4k[kt][r] = exp2f(s4k[kt][r] - m_run);
          ps += s4k[kt][r];
        }
      ps += __shfl_xor(ps, 16);
      ps += __shfl_xor(ps, 32);
      l_run += ps;

      s4v pf[4];
#pragma unroll
      for (int kt = 0; kt < 4; ++kt)
#pragma unroll
        for (int r = 0; r < 4; ++r) pf[kt][r] = (short)f2b(s4k[kt][r]);

      // ---- O^T += V^T * P^T  (pipelined: issue batch kt+1, wait batch kt)
#define PVK(KT, CURV, NXTV, LAST) do { \
        if (!(LAST)) { \
          const char* tbn = Vb + (((KT) + 1) * 4 + g) * 1024 + qi * 8; \
          _Pragma("unroll") \
          for (int dt = 0; dt < 8; ++dt) NXTV[dt] = tr_read(tbn, dt * 128); \
          asm volatile("s_waitcnt lgkmcnt(8)" ::: "memory"); \
        } else { \
          asm volatile("s_waitcnt lgkmcnt(0)" ::: "memory"); \
        } \
        __builtin_amdgcn_sched_barrier(0); \
        __builtin_amdgcn_s_setprio(1); \
        _Pragma("unroll") \
        for (int dt = 0; dt < 8; ++dt) mfma16(oacc[dt], CURV[dt], pf[KT]); \
        __builtin_amdgcn_s_setprio(0); \
      } while (0)
      PVK(0, vfA, vfB, 0);
      PVK(1, vfB, vfA, 0);
      PVK(2, vfA, vfB, 0);
      PVK(3, vfB, vfA, 1);
#undef PVK
    }
  }

  // ---- epilogue: O^T -> LDS (two half-passes) -> coalesced 32B bf16 stores
  __syncthreads();
  asm volatile("s_nop 7\n\ts_nop 7"
    : "+v"(oacc[0]), "+v"(oacc[1]), "+v"(oacc[2]), "+v"(oacc[3]),
      "+v"(oacc[4]), "+v"(oacc[5]), "+v"(oacc[6]), "+v"(oacc[7]));
  const float inv = 1.0f / l_run;
  float* Ost = (float*)smem;
  const int eq = tid >> 3, ed0 = (tid & 7) * 16;
  const int elw = eq >> 4, eql = eq & 15;
#pragma unroll
  for (int half = 0; half < 2; ++half) {
    if ((wv >> 2) == half) {
      const int lw = wv & 3;
#pragma unroll
      for (int dt = 0; dt < 8; ++dt)
#pragma unroll
        for (int r = 0; r < 4; ++r)
          Ost[lw * 2112 + qi * 132 + dt * 16 + g * 4 + r] = oacc[dt][r] * inv;
    }
    __syncthreads();
    const float* src = Ost + elw * 2112 + eql * 132 + ed0;
    f4v a0 = *(const f4v*)(src), a1 = *(const f4v*)(src + 4),
        a2 = *(const f4v*)(src + 8), a3 = *(const f4v*)(src + 12);
    u4v r0, r1;
    r0.x = pk2(a0[0], a0[1]); r0.y = pk2(a0[2], a0[3]);
    r0.z = pk2(a1[0], a1[1]); r0.w = pk2(a1[2], a1[3]);
    r1.x = pk2(a2[0], a2[1]); r1.y = pk2(a2[2], a2[3]);
    r1.z = pk2(a3[0], a3[1]); r1.w = pk2(a3[2], a3[3]);
    unsigned short* dst = ao + (size_t)(b * 2048 + q0 + half * 64 + eq) * 4096 + h * 128 + ed0;
    *(u4v*)dst = r0;
    *(u4v*)(dst + 8) = r1;
    __syncthreads();
  }
}

// ---------------------------------------------------------------------------
// Host launcher. Workspace layout (needs ws_size >= 268,435,456 B):
//   [0,32M)     xb bf16        [32M,80M)   wqkv bf16
//   [80M,112M)  wo bf16        [112M,208M) qkv bf16 partials C1|C2 (2x48M)
//                              (reused as attn_out bf16 after rope)
//   [208M,240M) q bf16         [240M,248M) k bf16    [248M,256M) v bf16
// ---------------------------------------------------------------------------
extern "C" void kernel_launch(void* const* d_in, const int* in_sizes, int n_in,
                              void* d_out, int out_size, void* d_ws, size_t ws_size,
                              hipStream_t stream) {
  (void)in_sizes; (void)n_in; (void)out_size; (void)ws_size;
  const float* x  = (const float*)d_in[0];
  const float* wq = (const float*)d_in[1];
  const float* wk = (const float*)d_in[2];
  const float* wv = (const float*)d_in[3];
  const float* wo = (const float*)d_in[4];
  const float* fr = (const float*)d_in[5];
  const float* fi = (const float*)d_in[6];

  float* out = (float*)d_out;
  float* xk  = out + 16777216;
  float* xv  = xk + 4194304;

  char* ws = (char*)d_ws;
  unsigned short* xb    = (unsigned short*)(ws);
  unsigned short* wqkvb = (unsigned short*)(ws + 33554432);
  unsigned short* wob   = (unsigned short*)(ws + 83886080);
  unsigned short* qkvb  = (unsigned short*)(ws + 117440512);  // C1|C2 bf16
  unsigned short* aob   = (unsigned short*)(ws + 117440512);  // reuse after rope
  unsigned short* qbuf  = (unsigned short*)(ws + 218103808);
  unsigned short* kbuf  = (unsigned short*)(ws + 251658240);
  unsigned short* vbuf  = (unsigned short*)(ws + 260046848);

  cvt_bf16<<<16384, 256, 0, stream>>>(x,  xb, 4194304);
  cvt_bf16<<<16384, 256, 0, stream>>>(wq, wqkvb, 4194304);
  cvt_bf16<<<4096,  256, 0, stream>>>(wk, wqkvb + 16777216, 1048576);
  cvt_bf16<<<4096,  256, 0, stream>>>(wv, wqkvb + 20971520, 1048576);
  cvt_bf16<<<16384, 256, 0, stream>>>(wo, wob, 4194304);

  // qkv: splitK (K halves of 2048), 768 blocks = 3 exact rounds on 256 CUs
  gemm_bt8<1><<<768, 512, 0, stream>>>(xb, wqkvb, qkvb, 4096, 6144, 4096, 2048, 384);
  rope_scatter<<<49152, 256, 0, stream>>>(qkvb, fr, fi, qbuf, kbuf, vbuf, xk, xv);
  attn_fwd<<<dim3(16, 32, 2), 512, 0, stream>>>(qbuf, kbuf, vbuf, aob);
  gemm_bt8<0><<<256, 512, 0, stream>>>(aob, wob, out, 4096, 4096, 4096, 4096, 256);
}

// Round 7
// 693.134 us; speedup vs baseline: 1.1258x; 1.1258x over previous
//
#include <hip/hip_runtime.h>
#include <hip/hip_bf16.h>

// ---------------------------------------------------------------------------
// Attention block: B=2 S=2048 D=4096 H=32 KV=8 HD=128 (GQA N_REP=4, causal)
// Pipeline: cvt -> GEMM8-splitK(qkv, bf16 partials) -> RoPE/sum/scatter
//           -> flash-attn(16w, q-tile 256) -> GEMM8(out)
// ---------------------------------------------------------------------------

typedef __attribute__((ext_vector_type(8))) short  s8v;   // 8 x bf16 (4 VGPR)
typedef __attribute__((ext_vector_type(4))) short  s4v;   // 4 x bf16 (2 VGPR)
typedef __attribute__((ext_vector_type(4))) float  f4v;
typedef __attribute__((ext_vector_type(2))) float  f2v;
typedef __attribute__((ext_vector_type(2))) unsigned int u2v;
typedef __attribute__((ext_vector_type(4))) unsigned int u4v;

typedef __attribute__((address_space(3))) void lds_void;
typedef __attribute__((address_space(1))) void g_void;

#define GLDS16(gp, lp) __builtin_amdgcn_global_load_lds((g_void*)(gp), (lds_void*)(lp), 16, 0, 0)

__device__ __forceinline__ unsigned short f2b(float f) {  // f32 -> bf16 RNE
  unsigned u = __builtin_bit_cast(unsigned, f);
  u += 0x7fffu + ((u >> 16) & 1u);
  return (unsigned short)(u >> 16);
}
__device__ __forceinline__ unsigned pk2(float a, float b) {
  return (unsigned)f2b(a) | ((unsigned)f2b(b) << 16);
}
__device__ __forceinline__ float b2f(unsigned short h) {
  return __builtin_bit_cast(float, (unsigned)h << 16);
}

// inline-asm MFMAs (volatile; s_nop guards at every MFMA->VALU read-back)
__device__ __forceinline__ void mfma32(f4v& d, s8v a, s8v b) {
  asm volatile("v_mfma_f32_16x16x32_bf16 %0, %1, %2, %0" : "+v"(d) : "v"(a), "v"(b));
}
__device__ __forceinline__ void mfma16(f4v& d, s4v a, s4v b) {
  asm volatile("v_mfma_f32_16x16x16_bf16 %0, %1, %2, %0" : "+v"(d) : "v"(a), "v"(b));
}
__device__ __forceinline__ s4v tr_read(const char* p, int imm) {
  s4v r;
  asm volatile("ds_read_b64_tr_b16 %0, %1 offset:%2"
               : "=v"(r) : "v"((lds_void*)p), "n"(imm));
  return r;
}

// ---------------------------------------------------------------------------
// f32 -> bf16 convert
// ---------------------------------------------------------------------------
__global__ __launch_bounds__(256) void cvt_bf16(const float* __restrict__ s,
                                                unsigned short* __restrict__ d, int n4) {
  const int i = blockIdx.x * 256 + threadIdx.x;
  if (i >= n4) return;
  f4v v = *(const f4v*)(s + (size_t)i * 4);
  u2v r;
  r.x = pk2(v[0], v[1]);
  r.y = pk2(v[2], v[3]);
  *(u2v*)(d + (size_t)i * 4) = r;
}

// ---------------------------------------------------------------------------
// 8-phase GEMM, C = A[M][Ks] * B[N][Ks]^T over K range [kOff, kOff+Klen).
// 256x256 tile, BK=64, 512 thr = 8 waves (2M x 4N), 128 KiB LDS double-buffer.
// (unchanged from round 5 — see that round's race analysis)
// ---------------------------------------------------------------------------
#define BAR      asm volatile("s_barrier" ::: "memory")
#define WLGKM    do { asm volatile("s_waitcnt lgkmcnt(0)" ::: "memory"); \
                      __builtin_amdgcn_sched_barrier(0); } while (0)
#define WVM4     do { asm volatile("s_waitcnt vmcnt(4)" ::: "memory"); \
                      __builtin_amdgcn_sched_barrier(0); } while (0)

template <int OUTB>
__global__ __launch_bounds__(512, 2) void gemm_bt8(const unsigned short* __restrict__ A,
                                                   const unsigned short* __restrict__ Bp,
                                                   void* __restrict__ Cout,
                                                   int M, int N, int Ks, int Klen,
                                                   int nTiles) {
  __shared__ __align__(16) char smem[131072];
  const int tid = threadIdx.x, lane = tid & 63, wv = tid >> 6;
  const int qi = lane & 15, g = lane >> 4;
  const int wm = wv >> 2, wn = wv & 3;

  const int nwg = gridDim.x, cpx = nwg >> 3;
  const int id = blockIdx.x;
  const int swz = (id & 7) * cpx + (id >> 3);
  const int half = swz / nTiles;
  const int tile = swz - half * nTiles;
  const int kOff = half * Klen;
  const int MT = M >> 8;
  const int m0 = (tile % MT) * 256, n0 = (tile / MT) * 256;
  const int NT = Klen >> 6;

  const int srowo = wv * 8 + (lane >> 3);
  const int scole = ((lane & 7) ^ (lane >> 3)) << 3;
  const size_t rA = (size_t)(m0 + srowo) * Ks + kOff + scole;
  const size_t rB = (size_t)(n0 + srowo) * Ks + kOff + scole;
  char* sdA = smem + wv * 1024;
  char* sdB = smem + 32768 + wv * 1024;

#define STG_A(D, H, KT) do { \
    GLDS16(A + rA + (size_t)((H)*128) * Ks + (size_t)(KT)*64,      sdA + (D)*65536 + (H)*16384); \
    GLDS16(A + rA + (size_t)((H)*128 + 64) * Ks + (size_t)(KT)*64, sdA + (D)*65536 + (H)*16384 + 8192); } while (0)
#define STG_B(D, H, KT) do { \
    GLDS16(Bp + rB + (size_t)((H)*128) * Ks + (size_t)(KT)*64,      sdB + (D)*65536 + (H)*16384); \
    GLDS16(Bp + rB + (size_t)((H)*128 + 64) * Ks + (size_t)(KT)*64, sdB + (D)*65536 + (H)*16384 + 8192); } while (0)

  const int sw = (qi & 7) << 4;
  const char* frA = smem + (wm * 128 + qi) * 128;
  const char* frB = smem + 32768 + (wn * 64 + qi) * 128;

#define RDA4(D, F0) do { _Pragma("unroll") for (int f_ = 0; f_ < 4; ++f_) \
    _Pragma("unroll") for (int k_ = 0; k_ < 2; ++k_) \
      a[(F0) + f_][k_] = *(const s8v*)(frA + (D)*65536 + ((F0) + f_) * 2048 + (((k_ << 6) + (g << 4)) ^ sw)); } while (0)
#define RDB2(D, N0) do { _Pragma("unroll") for (int n_ = 0; n_ < 2; ++n_) \
    _Pragma("unroll") for (int k_ = 0; k_ < 2; ++k_) \
      b[(N0) + n_][k_] = *(const s8v*)(frB + (D)*65536 + ((N0) + n_) * 2048 + (((k_ << 6) + (g << 4)) ^ sw)); } while (0)
#define MQUAD(F0, N0) do { __builtin_amdgcn_s_setprio(1); \
    _Pragma("unroll") for (int f_ = 0; f_ < 4; ++f_) \
    _Pragma("unroll") for (int n_ = 0; n_ < 2; ++n_) \
    _Pragma("unroll") for (int k_ = 0; k_ < 2; ++k_) \
      mfma32(acc[(F0) + f_][(N0) + n_], a[(F0) + f_][k_], b[(N0) + n_][k_]); \
    __builtin_amdgcn_s_setprio(0); } while (0)

  f4v acc[8][4];
#pragma unroll
  for (int i = 0; i < 8; ++i)
#pragma unroll
    for (int j = 0; j < 4; ++j) acc[i][j] = (f4v)0.0f;

  STG_A(0, 0, 0); STG_A(0, 1, 0);
  STG_B(0, 0, 0); STG_B(0, 1, 0);
  STG_A(1, 0, 1); STG_A(1, 1, 1);
  WVM4;
  BAR;

  s8v a[8][2], b[4][2];
#pragma unroll 1
  for (int it = 0; it < NT / 2; ++it) {
    const int t = 2 * it;
    const int k2 = (t + 2 < NT) ? t + 2 : NT - 1;
    const int k3 = (t + 3 < NT) ? t + 3 : NT - 1;
    RDA4(0, 0); RDB2(0, 0);
    STG_B(1, 0, t + 1);
    BAR; WLGKM; MQUAD(0, 0); BAR;
    RDA4(0, 4);
    STG_B(1, 1, t + 1);
    BAR; WLGKM; MQUAD(4, 0); BAR;
    RDB2(0, 2);
    STG_A(0, 0, k2);
    BAR; WLGKM; MQUAD(0, 2); BAR;
    STG_A(0, 1, k2);
    BAR; WLGKM; MQUAD(4, 2);
    WVM4;
    BAR;
    RDA4(1, 0); RDB2(1, 0);
    STG_B(0, 0, k2);
    BAR; WLGKM; MQUAD(0, 0); BAR;
    RDA4(1, 4);
    STG_B(0, 1, k2);
    BAR; WLGKM; MQUAD(4, 0); BAR;
    RDB2(1, 2);
    STG_A(1, 0, k3);
    BAR; WLGKM; MQUAD(0, 2); BAR;
    STG_A(1, 1, k3);
    BAR; WLGKM; MQUAD(4, 2);
    WVM4;
    BAR;
  }

  asm volatile("s_waitcnt vmcnt(0)" ::: "memory");
  asm volatile("s_nop 7\n\ts_nop 7" ::: "memory");
  const int r4 = g * 4;
  if (OUTB) {
    unsigned short* Cb = (unsigned short*)Cout + (size_t)half * M * N;
#pragma unroll
    for (int fm = 0; fm < 8; ++fm)
#pragma unroll
      for (int fn = 0; fn < 4; ++fn)
#pragma unroll
        for (int r = 0; r < 4; ++r)
          Cb[(size_t)(m0 + wm * 128 + fm * 16 + r4 + r) * N + (n0 + wn * 64 + fn * 16 + qi)] =
              f2b(acc[fm][fn][r]);
  } else {
    float* Cf = (float*)Cout;
#pragma unroll
    for (int fm = 0; fm < 8; ++fm)
#pragma unroll
      for (int fn = 0; fn < 4; ++fn)
#pragma unroll
        for (int r = 0; r < 4; ++r)
          Cf[(size_t)(m0 + wm * 128 + fm * 16 + r4 + r) * N + (n0 + wn * 64 + fn * 16 + qi)] =
              acc[fm][fn][r];
  }
}

// ---------------------------------------------------------------------------
// RoPE + splitK-sum + scatter (unchanged from round 5)
// ---------------------------------------------------------------------------
__global__ __launch_bounds__(256) void rope_scatter(
    const unsigned short* __restrict__ qkvp, const float* __restrict__ fr,
    const float* __restrict__ fi,
    unsigned short* __restrict__ qb, unsigned short* __restrict__ kb,
    unsigned short* __restrict__ vbuf, float* __restrict__ xk, float* __restrict__ xv) {
  const int idx = blockIdx.x * 256 + threadIdx.x;
  const int token = idx / 3072;
  const int col2  = (idx - token * 3072) * 2;
  const int pos   = token & 2047;
  const unsigned u1 = *(const unsigned*)(qkvp + (size_t)token * 6144 + col2);
  const unsigned u2 = *(const unsigned*)(qkvp + 25165824u + (size_t)token * 6144 + col2);
  float v0 = b2f((unsigned short)u1) + b2f((unsigned short)u2);
  float v1 = b2f((unsigned short)(u1 >> 16)) + b2f((unsigned short)(u2 >> 16));
  if (col2 < 4096) {
    const int j = (col2 & 127) >> 1;
    const float cr = fr[pos * 64 + j], ci = fi[pos * 64 + j];
    const float a = v0 * cr - ci * v1;
    const float o = v0 * ci + v1 * cr;
    *(unsigned*)(qb + (size_t)token * 4096 + col2) = pk2(a, o);
  } else if (col2 < 5120) {
    const int lc = col2 - 4096;
    const int j = (lc & 127) >> 1;
    const float cr = fr[pos * 64 + j], ci = fi[pos * 64 + j];
    const float a = v0 * cr - ci * v1;
    const float o = v0 * ci + v1 * cr;
    *(unsigned*)(kb + (size_t)token * 1024 + lc) = pk2(a, o);
    f2v w; w.x = a; w.y = o;
    *(f2v*)(xk + (size_t)token * 1024 + lc) = w;
  } else {
    const int lc = col2 - 5120;
    *(unsigned*)(vbuf + (size_t)token * 1024 + lc) = pk2(v0, v1);
    f2v w; w.x = v0; w.y = v1;
    *(f2v*)(xv + (size_t)token * 1024 + lc) = w;
  }
}

// ---------------------------------------------------------------------------
// Causal GQA flash attention. Round-5 structure (single-buffer LDS, 2 barriers
// per tile, serial PV batches) but 1024 thr = 16 waves x 16 q-rows (q-tile
// 256): each staged K/V tile serves 2x the q-rows; staging is ONE pass.
// ---------------------------------------------------------------------------
#define SCL_LOG2 0.12751744f   // (1/sqrt(128)) * log2(e)

__global__ __launch_bounds__(1024, 4) void attn_fwd(
    const unsigned short* __restrict__ qb, const unsigned short* __restrict__ kb,
    const unsigned short* __restrict__ vb, unsigned short* __restrict__ ao) {
  __shared__ __align__(16) char smem[33792];   // K 16384 | V 16384; epilogue stage
  unsigned short* Ks = (unsigned short*)smem;
  char* Vt = smem + 16384;

  const int tid = threadIdx.x, lane = tid & 63, wv = tid >> 6;   // wv 0..15
  const int qi = lane & 15, g = lane >> 4;
  const int qtb = 7 - blockIdx.x;             // long blocks launch first
  const int h = blockIdx.y, b = blockIdx.z;
  const int kvh = h >> 2;
  const int q0 = qtb * 256;
  const int qrow = q0 + wv * 16 + qi;

  s8v qf[4];
  {
    const unsigned short* qp = qb + (size_t)(b * 2048 + qrow) * 4096 + h * 128 + g * 8;
#pragma unroll
    for (int c = 0; c < 4; ++c) qf[c] = *(const s8v*)(qp + c * 32);
  }

  f4v oacc[8];
#pragma unroll
  for (int i = 0; i < 8; ++i) oacc[i] = (f4v)0.0f;
  float m_run = -3.0e38f, l_run = 0.0f;

  // staging: 1024 threads cover 64 rows x 128 cols in one pass
  const int trow = tid >> 4;                  // 0..63 (key row)
  const int tcol = (tid & 15) * 8;            // 0..120 (d chunk)
  const unsigned short* kg = kb + (size_t)b * 2048 * 1024 + kvh * 128 + tcol;
  const unsigned short* vg = vb + (size_t)b * 2048 * 1024 + kvh * 128 + tcol;

  const int kwo = trow * 256 + ((tcol * 2) ^ ((trow & 7) << 4));
  const int vkt = trow >> 4, vg4 = (trow >> 2) & 3, vkl = trow & 3;
  const int vdt = tcol >> 4, vdl = tcol & 15;
  const int vwo = ((vkt * 4 + vg4) * 8 + vdt) * 128 + vkl * 32 + vdl * 2;

  const int ntiles = 4 * qtb + 4;
  const int my_qmax = q0 + wv * 16 + 15;
  const int wq_lo = q0 + wv * 16;

  s8v kreg, vreg;                             // T14 prefetch registers
  kreg = *(const s8v*)(kg + (size_t)trow * 1024);
  vreg = *(const s8v*)(vg + (size_t)trow * 1024);

  for (int t = 0; t < ntiles; ++t) {
    __syncthreads();                          // consumers of tile t-1 done
    *(s8v*)((char*)Ks + kwo) = kreg;
    *(s8v*)(Vt + vwo) = vreg;
    __syncthreads();
    if (t + 1 < ntiles) {                     // issue next tile's loads now
      const size_t base = (size_t)(t + 1) * 64 * 1024;
      kreg = *(const s8v*)(kg + base + (size_t)trow * 1024);
      vreg = *(const s8v*)(vg + base + (size_t)trow * 1024);
    }
    const int k0 = t * 64;
    if (k0 <= my_qmax) {
      // ---- S^T[key][q] = K * Q^T
      f4v s4k[4];
#pragma unroll
      for (int kt = 0; kt < 4; ++kt) s4k[kt] = (f4v)0.0f;
      __builtin_amdgcn_s_setprio(1);
#pragma unroll
      for (int kt = 0; kt < 4; ++kt) {
        const char* kbase = (const char*)Ks + (kt * 16 + qi) * 256;
        const int sw = (qi & 7) << 4;
#pragma unroll
        for (int c = 0; c < 4; ++c) {
          s8v kf = *(const s8v*)(kbase + ((c * 64 + g * 16) ^ sw));
          mfma32(s4k[kt], kf, qf[c]);
        }
      }
      __builtin_amdgcn_s_setprio(0);
      asm volatile("s_nop 7\n\ts_nop 7"
        : "+v"(s4k[0]), "+v"(s4k[1]), "+v"(s4k[2]), "+v"(s4k[3]));

      // ---- scale (+mask only on partial tiles); per-lane running max
      float tm = -3.0e38f;
      if (k0 + 64 <= wq_lo) {                 // wave-uniform: fully unmasked
#pragma unroll
        for (int kt = 0; kt < 4; ++kt)
#pragma unroll
          for (int r = 0; r < 4; ++r) {
            s4k[kt][r] *= SCL_LOG2;
            tm = fmaxf(tm, s4k[kt][r]);
          }
      } else {                                // diagonal/partial tile
#pragma unroll
        for (int kt = 0; kt < 4; ++kt)
#pragma unroll
          for (int r = 0; r < 4; ++r) {
            const int keyg = k0 + kt * 16 + g * 4 + r;
            s4k[kt][r] = (keyg <= qrow) ? s4k[kt][r] * SCL_LOG2 : -3.0e38f;
            tm = fmaxf(tm, s4k[kt][r]);
          }
      }
      tm = fmaxf(tm, __shfl_xor(tm, 16));
      tm = fmaxf(tm, __shfl_xor(tm, 32));

      // ---- T13 defer-max: skip rescale when max growth <= 8
      if (!__all(tm - m_run <= 8.0f)) {
        const float m_new = fmaxf(m_run, tm);
        const float al = exp2f(m_run - m_new);
#pragma unroll
        for (int i = 0; i < 8; ++i) oacc[i] *= al;
        l_run *= al;
        m_run = m_new;
      }
      float ps = 0.0f;
#pragma unroll
      for (int kt = 0; kt < 4; ++kt)
#pragma unroll
        for (int r = 0; r < 4; ++r) {
          s4k[kt][r] = exp2f(s4k[kt][r] - m_run);
          ps += s4k[kt][r];
        }
      ps += __shfl_xor(ps, 16);
      ps += __shfl_xor(ps, 32);
      l_run += ps;

      s4v pf[4];
#pragma unroll
      for (int kt = 0; kt < 4; ++kt)
#pragma unroll
        for (int r = 0; r < 4; ++r) pf[kt][r] = (short)f2b(s4k[kt][r]);

      // ---- O^T += V^T * P^T   (A-frags via hardware transpose read)
#pragma unroll
      for (int kt = 0; kt < 4; ++kt) {
        const char* tb = Vt + (kt * 4 + g) * 1024 + qi * 8;
        s4v vf[8];
#pragma unroll
        for (int dt = 0; dt < 8; ++dt) vf[dt] = tr_read(tb, dt * 128);
        asm volatile("s_waitcnt lgkmcnt(0)" ::: "memory");
        __builtin_amdgcn_sched_barrier(0);
        __builtin_amdgcn_s_setprio(1);
#pragma unroll
        for (int dt = 0; dt < 8; ++dt) mfma16(oacc[dt], vf[dt], pf[kt]);
        __builtin_amdgcn_s_setprio(0);
      }
    }
  }

  // ---- epilogue: O^T -> LDS f32 (4 quarter-passes of 4 waves) -> bf16 stores
  __syncthreads();
  asm volatile("s_nop 7\n\ts_nop 7"
    : "+v"(oacc[0]), "+v"(oacc[1]), "+v"(oacc[2]), "+v"(oacc[3]),
      "+v"(oacc[4]), "+v"(oacc[5]), "+v"(oacc[6]), "+v"(oacc[7]));
  const float inv = 1.0f / l_run;
  float* Ost = (float*)smem;                  // [4 waves][16 q][132 f32] per pass
  const int er = tid >> 4;                    // 0..63 row-in-pass
  const int ec = (tid & 15) * 8;              // col0
#pragma unroll
  for (int p = 0; p < 4; ++p) {
    if ((wv >> 2) == p) {
      const int lw = wv & 3;
#pragma unroll
      for (int dt = 0; dt < 8; ++dt)
#pragma unroll
        for (int r = 0; r < 4; ++r)
          Ost[lw * 2112 + qi * 132 + dt * 16 + g * 4 + r] = oacc[dt][r] * inv;
    }
    __syncthreads();
    const float* src = Ost + (er >> 4) * 2112 + (er & 15) * 132 + ec;
    f4v a0 = *(const f4v*)(src), a1 = *(const f4v*)(src + 4);
    u4v r0;
    r0.x = pk2(a0[0], a0[1]); r0.y = pk2(a0[2], a0[3]);
    r0.z = pk2(a1[0], a1[1]); r0.w = pk2(a1[2], a1[3]);
    *(u4v*)(ao + (size_t)(b * 2048 + q0 + p * 64 + er) * 4096 + h * 128 + ec) = r0;
    __syncthreads();
  }
}

// ---------------------------------------------------------------------------
// Host launcher. Workspace layout (needs ws_size >= 268,435,456 B):
//   [0,32M)     xb bf16        [32M,80M)   wqkv bf16
//   [80M,112M)  wo bf16        [112M,208M) qkv bf16 partials C1|C2 (2x48M)
//                              (reused as attn_out bf16 after rope)
//   [208M,240M) q bf16         [240M,248M) k bf16    [248M,256M) v bf16
// ---------------------------------------------------------------------------
extern "C" void kernel_launch(void* const* d_in, const int* in_sizes, int n_in,
                              void* d_out, int out_size, void* d_ws, size_t ws_size,
                              hipStream_t stream) {
  (void)in_sizes; (void)n_in; (void)out_size; (void)ws_size;
  const float* x  = (const float*)d_in[0];
  const float* wq = (const float*)d_in[1];
  const float* wk = (const float*)d_in[2];
  const float* wv = (const float*)d_in[3];
  const float* wo = (const float*)d_in[4];
  const float* fr = (const float*)d_in[5];
  const float* fi = (const float*)d_in[6];

  float* out = (float*)d_out;
  float* xk  = out + 16777216;
  float* xv  = xk + 4194304;

  char* ws = (char*)d_ws;
  unsigned short* xb    = (unsigned short*)(ws);
  unsigned short* wqkvb = (unsigned short*)(ws + 33554432);
  unsigned short* wob   = (unsigned short*)(ws + 83886080);
  unsigned short* qkvb  = (unsigned short*)(ws + 117440512);  // C1|C2 bf16
  unsigned short* aob   = (unsigned short*)(ws + 117440512);  // reuse after rope
  unsigned short* qbuf  = (unsigned short*)(ws + 218103808);
  unsigned short* kbuf  = (unsigned short*)(ws + 251658240);
  unsigned short* vbuf  = (unsigned short*)(ws + 260046848);

  cvt_bf16<<<16384, 256, 0, stream>>>(x,  xb, 4194304);
  cvt_bf16<<<16384, 256, 0, stream>>>(wq, wqkvb, 4194304);
  cvt_bf16<<<4096,  256, 0, stream>>>(wk, wqkvb + 16777216, 1048576);
  cvt_bf16<<<4096,  256, 0, stream>>>(wv, wqkvb + 20971520, 1048576);
  cvt_bf16<<<16384, 256, 0, stream>>>(wo, wob, 4194304);

  // qkv: splitK (K halves of 2048), 768 blocks = 3 exact rounds on 256 CUs
  gemm_bt8<1><<<768, 512, 0, stream>>>(xb, wqkvb, qkvb, 4096, 6144, 4096, 2048, 384);
  rope_scatter<<<49152, 256, 0, stream>>>(qkvb, fr, fi, qbuf, kbuf, vbuf, xk, xv);
  attn_fwd<<<dim3(8, 32, 2), 1024, 0, stream>>>(qbuf, kbuf, vbuf, aob);
  gemm_bt8<0><<<256, 512, 0, stream>>>(aob, wob, out, 4096, 4096, 4096, 4096, 256);
}

// Round 8
// 663.182 us; speedup vs baseline: 1.1766x; 1.0452x over previous
//
#include <hip/hip_runtime.h>
#include <hip/hip_bf16.h>

// ---------------------------------------------------------------------------
// Attention block: B=2 S=2048 D=4096 H=32 KV=8 HD=128 (GQA N_REP=4, causal)
// Pipeline: cvt -> GEMM8-splitK(qkv, bf16 partials) -> RoPE/sum/scatter
//           -> flash-attn(8w, 32x32 MFMA, q-tile 256) -> GEMM8(out)
// ---------------------------------------------------------------------------

typedef __attribute__((ext_vector_type(8)))  short s8v;   // 8 x bf16 (4 VGPR)
typedef __attribute__((ext_vector_type(4)))  short s4v;   // 4 x bf16 (2 VGPR)
typedef __attribute__((ext_vector_type(4)))  float f4v;
typedef __attribute__((ext_vector_type(16))) float f16v;  // 32x32 MFMA acc
typedef __attribute__((ext_vector_type(2)))  float f2v;
typedef __attribute__((ext_vector_type(2))) unsigned int u2v;
typedef __attribute__((ext_vector_type(4))) unsigned int u4v;

typedef __attribute__((address_space(3))) void lds_void;
typedef __attribute__((address_space(1))) void g_void;

#define GLDS16(gp, lp) __builtin_amdgcn_global_load_lds((g_void*)(gp), (lds_void*)(lp), 16, 0, 0)

__device__ __forceinline__ unsigned short f2b(float f) {  // f32 -> bf16 RNE
  unsigned u = __builtin_bit_cast(unsigned, f);
  u += 0x7fffu + ((u >> 16) & 1u);
  return (unsigned short)(u >> 16);
}
__device__ __forceinline__ unsigned pk2(float a, float b) {
  return (unsigned)f2b(a) | ((unsigned)f2b(b) << 16);
}
__device__ __forceinline__ float b2f(unsigned short h) {
  return __builtin_bit_cast(float, (unsigned)h << 16);
}

// inline-asm MFMAs (volatile; s_nop guards at every MFMA->VALU read-back)
__device__ __forceinline__ void mfma32(f4v& d, s8v a, s8v b) {
  asm volatile("v_mfma_f32_16x16x32_bf16 %0, %1, %2, %0" : "+v"(d) : "v"(a), "v"(b));
}
__device__ __forceinline__ void mfma3216(f16v& d, s8v a, s8v b) {
  asm volatile("v_mfma_f32_32x32x16_bf16 %0, %1, %2, %0" : "+v"(d) : "v"(a), "v"(b));
}
__device__ __forceinline__ s4v tr_read(const char* p, int imm) {
  s4v r;
  asm volatile("ds_read_b64_tr_b16 %0, %1 offset:%2"
               : "=v"(r) : "v"((lds_void*)p), "n"(imm));
  return r;
}

// ---------------------------------------------------------------------------
// f32 -> bf16 convert
// ---------------------------------------------------------------------------
__global__ __launch_bounds__(256) void cvt_bf16(const float* __restrict__ s,
                                                unsigned short* __restrict__ d, int n4) {
  const int i = blockIdx.x * 256 + threadIdx.x;
  if (i >= n4) return;
  f4v v = *(const f4v*)(s + (size_t)i * 4);
  u2v r;
  r.x = pk2(v[0], v[1]);
  r.y = pk2(v[2], v[3]);
  *(u2v*)(d + (size_t)i * 4) = r;
}

// ---------------------------------------------------------------------------
// 8-phase GEMM, C = A[M][Ks] * B[N][Ks]^T over K range [kOff, kOff+Klen).
// 256x256 tile, BK=64, 512 thr = 8 waves (2M x 4N), 128 KiB LDS double-buffer.
// (unchanged from round 5 — see that round's race analysis)
// ---------------------------------------------------------------------------
#define BAR      asm volatile("s_barrier" ::: "memory")
#define WLGKM    do { asm volatile("s_waitcnt lgkmcnt(0)" ::: "memory"); \
                      __builtin_amdgcn_sched_barrier(0); } while (0)
#define WVM4     do { asm volatile("s_waitcnt vmcnt(4)" ::: "memory"); \
                      __builtin_amdgcn_sched_barrier(0); } while (0)

template <int OUTB>
__global__ __launch_bounds__(512, 2) void gemm_bt8(const unsigned short* __restrict__ A,
                                                   const unsigned short* __restrict__ Bp,
                                                   void* __restrict__ Cout,
                                                   int M, int N, int Ks, int Klen,
                                                   int nTiles) {
  __shared__ __align__(16) char smem[131072];
  const int tid = threadIdx.x, lane = tid & 63, wv = tid >> 6;
  const int qi = lane & 15, g = lane >> 4;
  const int wm = wv >> 2, wn = wv & 3;

  const int nwg = gridDim.x, cpx = nwg >> 3;
  const int id = blockIdx.x;
  const int swz = (id & 7) * cpx + (id >> 3);
  const int half = swz / nTiles;
  const int tile = swz - half * nTiles;
  const int kOff = half * Klen;
  const int MT = M >> 8;
  const int m0 = (tile % MT) * 256, n0 = (tile / MT) * 256;
  const int NT = Klen >> 6;

  const int srowo = wv * 8 + (lane >> 3);
  const int scole = ((lane & 7) ^ (lane >> 3)) << 3;
  const size_t rA = (size_t)(m0 + srowo) * Ks + kOff + scole;
  const size_t rB = (size_t)(n0 + srowo) * Ks + kOff + scole;
  char* sdA = smem + wv * 1024;
  char* sdB = smem + 32768 + wv * 1024;

#define STG_A(D, H, KT) do { \
    GLDS16(A + rA + (size_t)((H)*128) * Ks + (size_t)(KT)*64,      sdA + (D)*65536 + (H)*16384); \
    GLDS16(A + rA + (size_t)((H)*128 + 64) * Ks + (size_t)(KT)*64, sdA + (D)*65536 + (H)*16384 + 8192); } while (0)
#define STG_B(D, H, KT) do { \
    GLDS16(Bp + rB + (size_t)((H)*128) * Ks + (size_t)(KT)*64,      sdB + (D)*65536 + (H)*16384); \
    GLDS16(Bp + rB + (size_t)((H)*128 + 64) * Ks + (size_t)(KT)*64, sdB + (D)*65536 + (H)*16384 + 8192); } while (0)

  const int sw = (qi & 7) << 4;
  const char* frA = smem + (wm * 128 + qi) * 128;
  const char* frB = smem + 32768 + (wn * 64 + qi) * 128;

#define RDA4(D, F0) do { _Pragma("unroll") for (int f_ = 0; f_ < 4; ++f_) \
    _Pragma("unroll") for (int k_ = 0; k_ < 2; ++k_) \
      a[(F0) + f_][k_] = *(const s8v*)(frA + (D)*65536 + ((F0) + f_) * 2048 + (((k_ << 6) + (g << 4)) ^ sw)); } while (0)
#define RDB2(D, N0) do { _Pragma("unroll") for (int n_ = 0; n_ < 2; ++n_) \
    _Pragma("unroll") for (int k_ = 0; k_ < 2; ++k_) \
      b[(N0) + n_][k_] = *(const s8v*)(frB + (D)*65536 + ((N0) + n_) * 2048 + (((k_ << 6) + (g << 4)) ^ sw)); } while (0)
#define MQUAD(F0, N0) do { __builtin_amdgcn_s_setprio(1); \
    _Pragma("unroll") for (int f_ = 0; f_ < 4; ++f_) \
    _Pragma("unroll") for (int n_ = 0; n_ < 2; ++n_) \
    _Pragma("unroll") for (int k_ = 0; k_ < 2; ++k_) \
      mfma32(acc[(F0) + f_][(N0) + n_], a[(F0) + f_][k_], b[(N0) + n_][k_]); \
    __builtin_amdgcn_s_setprio(0); } while (0)

  f4v acc[8][4];
#pragma unroll
  for (int i = 0; i < 8; ++i)
#pragma unroll
    for (int j = 0; j < 4; ++j) acc[i][j] = (f4v)0.0f;

  STG_A(0, 0, 0); STG_A(0, 1, 0);
  STG_B(0, 0, 0); STG_B(0, 1, 0);
  STG_A(1, 0, 1); STG_A(1, 1, 1);
  WVM4;
  BAR;

  s8v a[8][2], b[4][2];
#pragma unroll 1
  for (int it = 0; it < NT / 2; ++it) {
    const int t = 2 * it;
    const int k2 = (t + 2 < NT) ? t + 2 : NT - 1;
    const int k3 = (t + 3 < NT) ? t + 3 : NT - 1;
    RDA4(0, 0); RDB2(0, 0);
    STG_B(1, 0, t + 1);
    BAR; WLGKM; MQUAD(0, 0); BAR;
    RDA4(0, 4);
    STG_B(1, 1, t + 1);
    BAR; WLGKM; MQUAD(4, 0); BAR;
    RDB2(0, 2);
    STG_A(0, 0, k2);
    BAR; WLGKM; MQUAD(0, 2); BAR;
    STG_A(0, 1, k2);
    BAR; WLGKM; MQUAD(4, 2);
    WVM4;
    BAR;
    RDA4(1, 0); RDB2(1, 0);
    STG_B(0, 0, k2);
    BAR; WLGKM; MQUAD(0, 0); BAR;
    RDA4(1, 4);
    STG_B(0, 1, k2);
    BAR; WLGKM; MQUAD(4, 0); BAR;
    RDB2(1, 2);
    STG_A(1, 0, k3);
    BAR; WLGKM; MQUAD(0, 2); BAR;
    STG_A(1, 1, k3);
    BAR; WLGKM; MQUAD(4, 2);
    WVM4;
    BAR;
  }

  asm volatile("s_waitcnt vmcnt(0)" ::: "memory");
  asm volatile("s_nop 7\n\ts_nop 7" ::: "memory");
  const int r4 = g * 4;
  if (OUTB) {
    unsigned short* Cb = (unsigned short*)Cout + (size_t)half * M * N;
#pragma unroll
    for (int fm = 0; fm < 8; ++fm)
#pragma unroll
      for (int fn = 0; fn < 4; ++fn)
#pragma unroll
        for (int r = 0; r < 4; ++r)
          Cb[(size_t)(m0 + wm * 128 + fm * 16 + r4 + r) * N + (n0 + wn * 64 + fn * 16 + qi)] =
              f2b(acc[fm][fn][r]);
  } else {
    float* Cf = (float*)Cout;
#pragma unroll
    for (int fm = 0; fm < 8; ++fm)
#pragma unroll
      for (int fn = 0; fn < 4; ++fn)
#pragma unroll
        for (int r = 0; r < 4; ++r)
          Cf[(size_t)(m0 + wm * 128 + fm * 16 + r4 + r) * N + (n0 + wn * 64 + fn * 16 + qi)] =
              acc[fm][fn][r];
  }
}

// ---------------------------------------------------------------------------
// RoPE + splitK-sum + scatter (unchanged from round 5)
// ---------------------------------------------------------------------------
__global__ __launch_bounds__(256) void rope_scatter(
    const unsigned short* __restrict__ qkvp, const float* __restrict__ fr,
    const float* __restrict__ fi,
    unsigned short* __restrict__ qb, unsigned short* __restrict__ kb,
    unsigned short* __restrict__ vbuf, float* __restrict__ xk, float* __restrict__ xv) {
  const int idx = blockIdx.x * 256 + threadIdx.x;
  const int token = idx / 3072;
  const int col2  = (idx - token * 3072) * 2;
  const int pos   = token & 2047;
  const unsigned u1 = *(const unsigned*)(qkvp + (size_t)token * 6144 + col2);
  const unsigned u2 = *(const unsigned*)(qkvp + 25165824u + (size_t)token * 6144 + col2);
  float v0 = b2f((unsigned short)u1) + b2f((unsigned short)u2);
  float v1 = b2f((unsigned short)(u1 >> 16)) + b2f((unsigned short)(u2 >> 16));
  if (col2 < 4096) {
    const int j = (col2 & 127) >> 1;
    const float cr = fr[pos * 64 + j], ci = fi[pos * 64 + j];
    const float a = v0 * cr - ci * v1;
    const float o = v0 * ci + v1 * cr;
    *(unsigned*)(qb + (size_t)token * 4096 + col2) = pk2(a, o);
  } else if (col2 < 5120) {
    const int lc = col2 - 4096;
    const int j = (lc & 127) >> 1;
    const float cr = fr[pos * 64 + j], ci = fi[pos * 64 + j];
    const float a = v0 * cr - ci * v1;
    const float o = v0 * ci + v1 * cr;
    *(unsigned*)(kb + (size_t)token * 1024 + lc) = pk2(a, o);
    f2v w; w.x = a; w.y = o;
    *(f2v*)(xk + (size_t)token * 1024 + lc) = w;
  } else {
    const int lc = col2 - 5120;
    *(unsigned*)(vbuf + (size_t)token * 1024 + lc) = pk2(v0, v1);
    f2v w; w.x = v0; w.y = v1;
    *(f2v*)(xv + (size_t)token * 1024 + lc) = w;
  }
}

// ---------------------------------------------------------------------------
// Causal GQA flash attention — 8 waves x 32 q-rows (q-tile 256), 32x32x16
// MFMA, KVBLK=64. Swapped QK^T (S^T = K*Q^T) -> P lane-local; in-register
// softmax; P->bf16 via v_cvt_pk_bf16_f32 + v_permlane32_swap_b32 (T12).
// Staging: global_load_lds with per-lane pre-swizzled sources (K: 16-slot
// XOR rows; V: tr-subtiled blocks). V double-buffered; counted vmcnt(2)
// schedule (T4): K lands before next QK, V stays in flight one tile.
// ---------------------------------------------------------------------------
#define SCL_LOG2 0.12751744f   // (1/sqrt(128)) * log2(e)

__global__ __launch_bounds__(512, 2) void attn_fwd(
    const unsigned short* __restrict__ qb, const unsigned short* __restrict__ kb,
    const unsigned short* __restrict__ vb, unsigned short* __restrict__ ao) {
  __shared__ __align__(16) char smem[49152];   // Ks 16K | V dbuf 2x16K; epi 32K f32
  char* const Ks = smem;
  const int tid = threadIdx.x, lane = tid & 63, wv = tid >> 6;
  const int q31 = lane & 31, hi = lane >> 5;
  const int qtb = 7 - blockIdx.x;              // long blocks launch first
  const int h = blockIdx.y, b = blockIdx.z, kvh = h >> 2;
  const int q0 = qtb * 256;
  const int qrow = q0 + wv * 32 + q31;

  // Q fragments in regs: qf[c] = Q[qrow][c*16 + hi*8 .. +8]
  s8v qf[8];
  {
    const unsigned short* qp = qb + (size_t)(b * 2048 + qrow) * 4096 + h * 128 + hi * 8;
#pragma unroll
    for (int c = 0; c < 8; ++c) qf[c] = *(const s8v*)(qp + c * 16);
  }

  f16v oacc[4];                                // O^T: [dt 4][16 f32] col q=lane&31
#pragma unroll
  for (int i = 0; i < 4; ++i) oacc[i] = (f16v)0.0f;
  float m_run = -3.0e38f, l_run = 0.0f;

  // ---- staging: per-lane swizzled global source, linear gload_lds dest ----
  // K rows [64][256B], slot s' holds src slot s'^(row&15)
  const unsigned short* ksrc[2]; char* kdst[2];
#pragma unroll
  for (int j = 0; j < 2; ++j) {
    const int r = wv * 8 + j * 4 + (lane >> 4);
    ksrc[j] = kb + (size_t)(b * 2048 + r) * 1024 + kvh * 128 + (((lane & 15) ^ (r & 15)) << 3);
    kdst[j] = Ks + (wv * 8 + j * 4) * 256;
  }
  // V tr-subtiled: block bb = [keygrp 16][dt16 8], content [4 key][16 d]
  const unsigned short* vsrc[2]; int vdoff[2];
#pragma unroll
  for (int j = 0; j < 2; ++j) {
    const int key = (wv * 2 + j) * 4 + ((lane & 7) >> 1);
    const int d = ((lane >> 3) & 7) * 16 + (lane & 1) * 8;
    vsrc[j] = vb + (size_t)(b * 2048 + key) * 1024 + kvh * 128 + d;
    vdoff[j] = (wv * 16 + j * 8) * 128;
  }

  const int ntiles = 4 * qtb + 4;
  const int my_qmax = q0 + wv * 32 + 31, wq_lo = q0 + wv * 32;

  // prologue: tile 0 (K -> Ks, V -> buf0); K must land, V may stay in flight
  GLDS16(ksrc[0], kdst[0]); GLDS16(ksrc[1], kdst[1]);
  GLDS16(vsrc[0], smem + 16384 + vdoff[0]); GLDS16(vsrc[1], smem + 16384 + vdoff[1]);
  asm volatile("s_waitcnt vmcnt(2)" ::: "memory");
  __builtin_amdgcn_sched_barrier(0);
  BAR;

  for (int t = 0; t < ntiles; ++t) {
    const int k0 = t * 64;
    const bool live = (k0 <= my_qmax);
    f16v s32a = (f16v)0.0f, s32b = (f16v)0.0f;   // S^T k-halves
    if (live) {
      __builtin_amdgcn_s_setprio(1);
#pragma unroll
      for (int c = 0; c < 8; ++c) {
        const int sl = ((2 * c + hi) ^ (q31 & 15)) << 4;
        s8v kfa = *(const s8v*)(Ks + q31 * 256 + sl);
        s8v kfb = *(const s8v*)(Ks + (32 + q31) * 256 + sl);
        mfma3216(s32a, kfa, qf[c]);
        mfma3216(s32b, kfb, qf[c]);
      }
      __builtin_amdgcn_s_setprio(0);
      asm volatile("s_nop 7\n\ts_nop 7\n\ts_nop 7" : "+v"(s32a), "+v"(s32b));
    }
    BAR;                                        // all waves done reading Ks / prev V
    {
      const size_t off = (size_t)((t + 1 < ntiles) ? t + 1 : t) * 65536;
      char* vbase = smem + 16384 + ((t + 1) & 1) * 16384;
      GLDS16(ksrc[0] + off, kdst[0]);
      GLDS16(ksrc[1] + off, kdst[1]);
      GLDS16(vsrc[0] + off, vbase + vdoff[0]);
      GLDS16(vsrc[1] + off, vbase + vdoff[1]);
    }
    asm volatile("s_waitcnt vmcnt(2)" ::: "memory");  // K(t+1) landed; V(t+1) in flight
    __builtin_amdgcn_sched_barrier(0);
    BAR;
    if (live) {
      // early-issue PV batch ks=0 (latency hides under softmax)
      const char* vbt = smem + 16384 + (t & 1) * 16384 + hi * 2048 +
                        ((lane >> 4) & 1) * 128 + ((lane & 15) << 3);
      s4v tA[8], tB[8];
#pragma unroll
      for (int u = 0; u < 8; ++u) tA[u] = tr_read(vbt, (u >> 1) * 256 + (u & 1) * 1024);

      // mask + scale; p[j] j = kh*16+reg, key = k0+kh*32+(j&3)+8*((j>>2)&3)+4*hi
      float p[32];
#pragma unroll
      for (int r = 0; r < 16; ++r) { p[r] = s32a[r]; p[16 + r] = s32b[r]; }
      float tm = -3.0e38f;
      if (k0 + 64 <= wq_lo) {                   // wave-uniform fully-unmasked
#pragma unroll
        for (int j = 0; j < 32; ++j) { p[j] *= SCL_LOG2; tm = fmaxf(tm, p[j]); }
      } else {
#pragma unroll
        for (int j = 0; j < 32; ++j) {
          const int keyg = k0 + (j >> 4) * 32 + (j & 3) + 8 * ((j >> 2) & 3) + 4 * hi;
          p[j] = (keyg <= qrow) ? p[j] * SCL_LOG2 : -3.0e38f;
          tm = fmaxf(tm, p[j]);
        }
      }
      tm = fmaxf(tm, __shfl_xor(tm, 32));       // partner holds other 32 keys

      if (!__all(tm - m_run <= 8.0f)) {         // T13 defer-max
        const float m_new = fmaxf(m_run, tm);
        const float al = exp2f(m_run - m_new);
#pragma unroll
        for (int i = 0; i < 4; ++i)
#pragma unroll
          for (int r = 0; r < 16; ++r) oacc[i][r] *= al;
        l_run *= al;
        m_run = m_new;
      }
      float ps = 0.0f;
#pragma unroll
      for (int j = 0; j < 32; ++j) { p[j] = exp2f(p[j] - m_run); ps += p[j]; }
      ps += __shfl_xor(ps, 32);
      l_run += ps;

      // P -> bf16 B-frags: 4 cvt_pk + 2 permlane32_swap per ks (T12)
      s8v pf[4];
#pragma unroll
      for (int ks = 0; ks < 4; ++ks) {
        unsigned c0, c1, c2, c3;
        asm("v_cvt_pk_bf16_f32 %0, %1, %2" : "=v"(c0) : "v"(p[ks*8+0]), "v"(p[ks*8+1]));
        asm("v_cvt_pk_bf16_f32 %0, %1, %2" : "=v"(c1) : "v"(p[ks*8+2]), "v"(p[ks*8+3]));
        asm("v_cvt_pk_bf16_f32 %0, %1, %2" : "=v"(c2) : "v"(p[ks*8+4]), "v"(p[ks*8+5]));
        asm("v_cvt_pk_bf16_f32 %0, %1, %2" : "=v"(c3) : "v"(p[ks*8+6]), "v"(p[ks*8+7]));
        asm volatile("v_permlane32_swap_b32 %0, %1" : "+v"(c0), "+v"(c2));
        asm volatile("v_permlane32_swap_b32 %0, %1" : "+v"(c1), "+v"(c3));
        u4v pw; pw.x = c0; pw.y = c1; pw.z = c2; pw.w = c3;
        pf[ks] = __builtin_bit_cast(s8v, pw);
      }

      // PV: O^T[dt] += V^T-frag * P^T-frag, 1-deep tr pipeline, counted lgkm
#define PVS(KS, CUR, NXT, LAST) do { \
        if (!(LAST)) { \
          _Pragma("unroll") for (int u = 0; u < 8; ++u) \
            NXT[u] = tr_read(vbt, ((KS)+1)*4096 + (u >> 1) * 256 + (u & 1) * 1024); \
          asm volatile("s_waitcnt lgkmcnt(8)" ::: "memory"); \
        } else { asm volatile("s_waitcnt lgkmcnt(0)" ::: "memory"); } \
        __builtin_amdgcn_sched_barrier(0); \
        __builtin_amdgcn_s_setprio(1); \
        _Pragma("unroll") for (int dt = 0; dt < 4; ++dt) { \
          s8v vf = __builtin_shufflevector(CUR[dt*2], CUR[dt*2+1], 0,1,2,3,4,5,6,7); \
          mfma3216(oacc[dt], vf, pf[KS]); } \
        __builtin_amdgcn_s_setprio(0); \
      } while (0)
      PVS(0, tA, tB, 0);
      PVS(1, tB, tA, 0);
      PVS(2, tA, tB, 0);
      PVS(3, tB, tA, 1);
#undef PVS
    }
  }

  // ---- epilogue: O^T -> swizzled f32 LDS (4 passes of 2 waves) -> bf16 ----
  asm volatile("s_waitcnt vmcnt(0) lgkmcnt(0)" ::: "memory");
  asm volatile("s_nop 7\n\ts_nop 7\n\ts_nop 7" ::: "memory");
  __syncthreads();
  const float inv = 1.0f / l_run;
  float* Ost = (float*)smem;                    // [64 q][128 d], word ^ ((q&7)<<2)
  const int er = tid >> 3, ew = (tid & 7) * 16;
#pragma unroll
  for (int pq = 0; pq < 4; ++pq) {
    if ((wv >> 1) == pq) {
      const int qip = (wv & 1) * 32 + q31;
#pragma unroll
      for (int dt = 0; dt < 4; ++dt)
#pragma unroll
        for (int r = 0; r < 16; ++r) {
          const int d = dt * 32 + (r & 3) + 8 * ((r >> 2) & 3) + 4 * hi;
          Ost[qip * 128 + (d ^ ((qip & 7) << 2))] = oacc[dt][r] * inv;
        }
    }
    __syncthreads();
    const int sw = (er & 7) << 2;
    f4v a0 = *(const f4v*)(Ost + er * 128 + ((ew + 0) ^ sw));
    f4v a1 = *(const f4v*)(Ost + er * 128 + ((ew + 4) ^ sw));
    f4v a2 = *(const f4v*)(Ost + er * 128 + ((ew + 8) ^ sw));
    f4v a3 = *(const f4v*)(Ost + er * 128 + ((ew + 12) ^ sw));
    u4v r0, r1;
    r0.x = pk2(a0[0], a0[1]); r0.y = pk2(a0[2], a0[3]);
    r0.z = pk2(a1[0], a1[1]); r0.w = pk2(a1[2], a1[3]);
    r1.x = pk2(a2[0], a2[1]); r1.y = pk2(a2[2], a2[3]);
    r1.z = pk2(a3[0], a3[1]); r1.w = pk2(a3[2], a3[3]);
    unsigned short* dst = ao + (size_t)(b * 2048 + q0 + pq * 64 + er) * 4096 + h * 128 + ew;
    *(u4v*)dst = r0;
    *(u4v*)(dst + 8) = r1;
    __syncthreads();
  }
}

// ---------------------------------------------------------------------------
// Host launcher. Workspace layout (needs ws_size >= 268,435,456 B):
//   [0,32M)     xb bf16        [32M,80M)   wqkv bf16
//   [80M,112M)  wo bf16        [112M,208M) qkv bf16 partials C1|C2 (2x48M)
//                              (reused as attn_out bf16 after rope)
//   [208M,240M) q bf16         [240M,248M) k bf16    [248M,256M) v bf16
// ---------------------------------------------------------------------------
extern "C" void kernel_launch(void* const* d_in, const int* in_sizes, int n_in,
                              void* d_out, int out_size, void* d_ws, size_t ws_size,
                              hipStream_t stream) {
  (void)in_sizes; (void)n_in; (void)out_size; (void)ws_size;
  const float* x  = (const float*)d_in[0];
  const float* wq = (const float*)d_in[1];
  const float* wk = (const float*)d_in[2];
  const float* wv = (const float*)d_in[3];
  const float* wo = (const float*)d_in[4];
  const float* fr = (const float*)d_in[5];
  const float* fi = (const float*)d_in[6];

  float* out = (float*)d_out;
  float* xk  = out + 16777216;
  float* xv  = xk + 4194304;

  char* ws = (char*)d_ws;
  unsigned short* xb    = (unsigned short*)(ws);
  unsigned short* wqkvb = (unsigned short*)(ws + 33554432);
  unsigned short* wob   = (unsigned short*)(ws + 83886080);
  unsigned short* qkvb  = (unsigned short*)(ws + 117440512);  // C1|C2 bf16
  unsigned short* aob   = (unsigned short*)(ws + 117440512);  // reuse after rope
  unsigned short* qbuf  = (unsigned short*)(ws + 218103808);
  unsigned short* kbuf  = (unsigned short*)(ws + 251658240);
  unsigned short* vbuf  = (unsigned short*)(ws + 260046848);

  cvt_bf16<<<16384, 256, 0, stream>>>(x,  xb, 4194304);
  cvt_bf16<<<16384, 256, 0, stream>>>(wq, wqkvb, 4194304);
  cvt_bf16<<<4096,  256, 0, stream>>>(wk, wqkvb + 16777216, 1048576);
  cvt_bf16<<<4096,  256, 0, stream>>>(wv, wqkvb + 20971520, 1048576);
  cvt_bf16<<<16384, 256, 0, stream>>>(wo, wob, 4194304);

  // qkv: splitK (K halves of 2048), 768 blocks = 3 exact rounds on 256 CUs
  gemm_bt8<1><<<768, 512, 0, stream>>>(xb, wqkvb, qkvb, 4096, 6144, 4096, 2048, 384);
  rope_scatter<<<49152, 256, 0, stream>>>(qkvb, fr, fi, qbuf, kbuf, vbuf, xk, xv);
  attn_fwd<<<dim3(8, 32, 2), 512, 0, stream>>>(qbuf, kbuf, vbuf, aob);
  gemm_bt8<0><<<256, 512, 0, stream>>>(aob, wob, out, 4096, 4096, 4096, 4096, 256);
}

// Round 9
// 652.352 us; speedup vs baseline: 1.1962x; 1.0166x over previous
//
#include <hip/hip_runtime.h>
#include <hip/hip_bf16.h>

// ---------------------------------------------------------------------------
// Attention block: B=2 S=2048 D=4096 H=32 KV=8 HD=128 (GQA N_REP=4, causal)
// Pipeline: cvt -> GEMM8-splitK(qkv, bf16 partials) -> RoPE/sum/scatter
//           -> flash-attn(8w, 32x32 MFMA, q-tile 256) -> GEMM8(out)
// ---------------------------------------------------------------------------

typedef __attribute__((ext_vector_type(8)))  short s8v;   // 8 x bf16 (4 VGPR)
typedef __attribute__((ext_vector_type(4)))  short s4v;   // 4 x bf16 (2 VGPR)
typedef __attribute__((ext_vector_type(4)))  float f4v;
typedef __attribute__((ext_vector_type(16))) float f16v;  // 32x32 MFMA acc
typedef __attribute__((ext_vector_type(2)))  float f2v;
typedef __attribute__((ext_vector_type(2))) unsigned int u2v;
typedef __attribute__((ext_vector_type(4))) unsigned int u4v;

typedef __attribute__((address_space(3))) void lds_void;
typedef __attribute__((address_space(1))) void g_void;

#define GLDS16(gp, lp) __builtin_amdgcn_global_load_lds((g_void*)(gp), (lds_void*)(lp), 16, 0, 0)

__device__ __forceinline__ unsigned short f2b(float f) {  // f32 -> bf16 RNE
  unsigned u = __builtin_bit_cast(unsigned, f);
  u += 0x7fffu + ((u >> 16) & 1u);
  return (unsigned short)(u >> 16);
}
__device__ __forceinline__ unsigned pk2(float a, float b) {
  return (unsigned)f2b(a) | ((unsigned)f2b(b) << 16);
}
__device__ __forceinline__ float b2f(unsigned short h) {
  return __builtin_bit_cast(float, (unsigned)h << 16);
}

// inline-asm MFMAs (volatile; s_nop guards at every MFMA->VALU read-back)
__device__ __forceinline__ void mfma32(f4v& d, s8v a, s8v b) {
  asm volatile("v_mfma_f32_16x16x32_bf16 %0, %1, %2, %0" : "+v"(d) : "v"(a), "v"(b));
}
__device__ __forceinline__ void mfma3216(f16v& d, s8v a, s8v b) {
  asm volatile("v_mfma_f32_32x32x16_bf16 %0, %1, %2, %0" : "+v"(d) : "v"(a), "v"(b));
}
__device__ __forceinline__ s4v tr_read(const char* p, int imm) {
  s4v r;
  asm volatile("ds_read_b64_tr_b16 %0, %1 offset:%2"
               : "=v"(r) : "v"((lds_void*)p), "n"(imm));
  return r;
}

// ---------------------------------------------------------------------------
// f32 -> bf16 convert
// ---------------------------------------------------------------------------
__global__ __launch_bounds__(256) void cvt_bf16(const float* __restrict__ s,
                                                unsigned short* __restrict__ d, int n4) {
  const int i = blockIdx.x * 256 + threadIdx.x;
  if (i >= n4) return;
  f4v v = *(const f4v*)(s + (size_t)i * 4);
  u2v r;
  r.x = pk2(v[0], v[1]);
  r.y = pk2(v[2], v[3]);
  *(u2v*)(d + (size_t)i * 4) = r;
}

// ---------------------------------------------------------------------------
// 8-phase GEMM, C = A[M][Ks] * B[N][Ks]^T over K range [kOff, kOff+Klen).
// 256x256 tile, BK=64, 512 thr = 8 waves (2M x 4N), 128 KiB LDS double-buffer.
// Round-9 schedule (deep prefetch): stage slots ph2: t+2.A0; ph3: t+2.A1+B0+B1
// + vmcnt(8); ph6: t+3.A0; ph7: t+3.A1+B0+B1 + vmcnt(8). Gates leave exactly
// the next tile's 8 loads in flight; youngest-needed load has 4 phases of
// issue-to-gate slack (was 2). Write-lands legality: buf.A halves last read
// ph0/ph1 (restage ph2/ph3), buf.B last read ph2 (restage ph3) — all after
// the respective closing barriers; mirrored for buf1 at ph4-7.
// ---------------------------------------------------------------------------
#define BAR      asm volatile("s_barrier" ::: "memory")
#define WLGKM    do { asm volatile("s_waitcnt lgkmcnt(0)" ::: "memory"); \
                      __builtin_amdgcn_sched_barrier(0); } while (0)
#define WVM8     do { asm volatile("s_waitcnt vmcnt(8)" ::: "memory"); \
                      __builtin_amdgcn_sched_barrier(0); } while (0)

template <int OUTB>
__global__ __launch_bounds__(512, 2) void gemm_bt8(const unsigned short* __restrict__ A,
                                                   const unsigned short* __restrict__ Bp,
                                                   void* __restrict__ Cout,
                                                   int M, int N, int Ks, int Klen,
                                                   int nTiles) {
  __shared__ __align__(16) char smem[131072];
  const int tid = threadIdx.x, lane = tid & 63, wv = tid >> 6;
  const int qi = lane & 15, g = lane >> 4;
  const int wm = wv >> 2, wn = wv & 3;

  const int nwg = gridDim.x, cpx = nwg >> 3;
  const int id = blockIdx.x;
  const int swz = (id & 7) * cpx + (id >> 3);
  const int half = swz / nTiles;
  const int tile = swz - half * nTiles;
  const int kOff = half * Klen;
  const int MT = M >> 8;
  const int m0 = (tile % MT) * 256, n0 = (tile / MT) * 256;
  const int NT = Klen >> 6;

  const int srowo = wv * 8 + (lane >> 3);
  const int scole = ((lane & 7) ^ (lane >> 3)) << 3;
  const size_t rA = (size_t)(m0 + srowo) * Ks + kOff + scole;
  const size_t rB = (size_t)(n0 + srowo) * Ks + kOff + scole;
  char* sdA = smem + wv * 1024;
  char* sdB = smem + 32768 + wv * 1024;

#define STG_A(D, H, KT) do { \
    GLDS16(A + rA + (size_t)((H)*128) * Ks + (size_t)(KT)*64,      sdA + (D)*65536 + (H)*16384); \
    GLDS16(A + rA + (size_t)((H)*128 + 64) * Ks + (size_t)(KT)*64, sdA + (D)*65536 + (H)*16384 + 8192); } while (0)
#define STG_B(D, H, KT) do { \
    GLDS16(Bp + rB + (size_t)((H)*128) * Ks + (size_t)(KT)*64,      sdB + (D)*65536 + (H)*16384); \
    GLDS16(Bp + rB + (size_t)((H)*128 + 64) * Ks + (size_t)(KT)*64, sdB + (D)*65536 + (H)*16384 + 8192); } while (0)

  const int sw = (qi & 7) << 4;
  const char* frA = smem + (wm * 128 + qi) * 128;
  const char* frB = smem + 32768 + (wn * 64 + qi) * 128;

#define RDA4(D, F0) do { _Pragma("unroll") for (int f_ = 0; f_ < 4; ++f_) \
    _Pragma("unroll") for (int k_ = 0; k_ < 2; ++k_) \
      a[(F0) + f_][k_] = *(const s8v*)(frA + (D)*65536 + ((F0) + f_) * 2048 + (((k_ << 6) + (g << 4)) ^ sw)); } while (0)
#define RDB2(D, N0) do { _Pragma("unroll") for (int n_ = 0; n_ < 2; ++n_) \
    _Pragma("unroll") for (int k_ = 0; k_ < 2; ++k_) \
      b[(N0) + n_][k_] = *(const s8v*)(frB + (D)*65536 + ((N0) + n_) * 2048 + (((k_ << 6) + (g << 4)) ^ sw)); } while (0)
#define MQUAD(F0, N0) do { __builtin_amdgcn_s_setprio(1); \
    _Pragma("unroll") for (int f_ = 0; f_ < 4; ++f_) \
    _Pragma("unroll") for (int n_ = 0; n_ < 2; ++n_) \
    _Pragma("unroll") for (int k_ = 0; k_ < 2; ++k_) \
      mfma32(acc[(F0) + f_][(N0) + n_], a[(F0) + f_][k_], b[(N0) + n_][k_]); \
    __builtin_amdgcn_s_setprio(0); } while (0)

  f4v acc[8][4];
#pragma unroll
  for (int i = 0; i < 8; ++i)
#pragma unroll
    for (int j = 0; j < 4; ++j) acc[i][j] = (f4v)0.0f;

  // prologue: tile0 (8 loads) + tile1 (8 loads); drain tile0, keep tile1 flying
  STG_A(0, 0, 0); STG_A(0, 1, 0); STG_B(0, 0, 0); STG_B(0, 1, 0);
  STG_A(1, 0, 1); STG_A(1, 1, 1); STG_B(1, 0, 1); STG_B(1, 1, 1);
  WVM8;
  BAR;

  s8v a[8][2], b[4][2];
#pragma unroll 1
  for (int it = 0; it < NT / 2; ++it) {
    const int t = 2 * it;
    const int k2 = (t + 2 < NT) ? t + 2 : NT - 1;   // clamped: dest dead on tail
    const int k3 = (t + 3 < NT) ? t + 3 : NT - 1;
    // ---- phase 0: buf0 quad(0,0)
    RDA4(0, 0); RDB2(0, 0);
    BAR; WLGKM; MQUAD(0, 0); BAR;
    // ---- phase 1: buf0 quad(1,0)
    RDA4(0, 4);
    BAR; WLGKM; MQUAD(4, 0); BAR;
    // ---- phase 2: buf0 quad(0,1); stage t+2.A0
    RDB2(0, 2);
    STG_A(0, 0, k2);
    BAR; WLGKM; MQUAD(0, 2); BAR;
    // ---- phase 3: buf0 quad(1,1); stage t+2.A1+B0+B1; gate tile t+1
    STG_A(0, 1, k2); STG_B(0, 0, k2); STG_B(0, 1, k2);
    BAR; WLGKM; MQUAD(4, 2);
    WVM8;
    BAR;
    // ---- phase 4: buf1 quad(0,0)
    RDA4(1, 0); RDB2(1, 0);
    BAR; WLGKM; MQUAD(0, 0); BAR;
    // ---- phase 5: buf1 quad(1,0)
    RDA4(1, 4);
    BAR; WLGKM; MQUAD(4, 0); BAR;
    // ---- phase 6: buf1 quad(0,1); stage t+3.A0
    RDB2(1, 2);
    STG_A(1, 0, k3);
    BAR; WLGKM; MQUAD(0, 2); BAR;
    // ---- phase 7: buf1 quad(1,1); stage t+3.A1+B0+B1; gate tile t+2
    STG_A(1, 1, k3); STG_B(1, 0, k3); STG_B(1, 1, k3);
    BAR; WLGKM; MQUAD(4, 2);
    WVM8;
    BAR;
  }

  asm volatile("s_waitcnt vmcnt(0)" ::: "memory");
  asm volatile("s_nop 7\n\ts_nop 7" ::: "memory");   // MFMA->VALU hazard guard
  const int r4 = g * 4;
  if (OUTB) {
    unsigned short* Cb = (unsigned short*)Cout + (size_t)half * M * N;
#pragma unroll
    for (int fm = 0; fm < 8; ++fm)
#pragma unroll
      for (int fn = 0; fn < 4; ++fn)
#pragma unroll
        for (int r = 0; r < 4; ++r)
          Cb[(size_t)(m0 + wm * 128 + fm * 16 + r4 + r) * N + (n0 + wn * 64 + fn * 16 + qi)] =
              f2b(acc[fm][fn][r]);
  } else {
    float* Cf = (float*)Cout;
#pragma unroll
    for (int fm = 0; fm < 8; ++fm)
#pragma unroll
      for (int fn = 0; fn < 4; ++fn)
#pragma unroll
        for (int r = 0; r < 4; ++r)
          Cf[(size_t)(m0 + wm * 128 + fm * 16 + r4 + r) * N + (n0 + wn * 64 + fn * 16 + qi)] =
              acc[fm][fn][r];
  }
}

// ---------------------------------------------------------------------------
// RoPE + splitK-sum + scatter (unchanged)
// ---------------------------------------------------------------------------
__global__ __launch_bounds__(256) void rope_scatter(
    const unsigned short* __restrict__ qkvp, const float* __restrict__ fr,
    const float* __restrict__ fi,
    unsigned short* __restrict__ qb, unsigned short* __restrict__ kb,
    unsigned short* __restrict__ vbuf, float* __restrict__ xk, float* __restrict__ xv) {
  const int idx = blockIdx.x * 256 + threadIdx.x;
  const int token = idx / 3072;
  const int col2  = (idx - token * 3072) * 2;
  const int pos   = token & 2047;
  const unsigned u1 = *(const unsigned*)(qkvp + (size_t)token * 6144 + col2);
  const unsigned u2 = *(const unsigned*)(qkvp + 25165824u + (size_t)token * 6144 + col2);
  float v0 = b2f((unsigned short)u1) + b2f((unsigned short)u2);
  float v1 = b2f((unsigned short)(u1 >> 16)) + b2f((unsigned short)(u2 >> 16));
  if (col2 < 4096) {
    const int j = (col2 & 127) >> 1;
    const float cr = fr[pos * 64 + j], ci = fi[pos * 64 + j];
    const float a = v0 * cr - ci * v1;
    const float o = v0 * ci + v1 * cr;
    *(unsigned*)(qb + (size_t)token * 4096 + col2) = pk2(a, o);
  } else if (col2 < 5120) {
    const int lc = col2 - 4096;
    const int j = (lc & 127) >> 1;
    const float cr = fr[pos * 64 + j], ci = fi[pos * 64 + j];
    const float a = v0 * cr - ci * v1;
    const float o = v0 * ci + v1 * cr;
    *(unsigned*)(kb + (size_t)token * 1024 + lc) = pk2(a, o);
    f2v w; w.x = a; w.y = o;
    *(f2v*)(xk + (size_t)token * 1024 + lc) = w;
  } else {
    const int lc = col2 - 5120;
    *(unsigned*)(vbuf + (size_t)token * 1024 + lc) = pk2(v0, v1);
    f2v w; w.x = v0; w.y = v1;
    *(f2v*)(xv + (size_t)token * 1024 + lc) = w;
  }
}

// ---------------------------------------------------------------------------
// Causal GQA flash attention — 8 waves x 32 q-rows (q-tile 256), 32x32x16
// MFMA, KVBLK=64 (unchanged from round 8, proven).
// ---------------------------------------------------------------------------
#define SCL_LOG2 0.12751744f   // (1/sqrt(128)) * log2(e)

__global__ __launch_bounds__(512, 2) void attn_fwd(
    const unsigned short* __restrict__ qb, const unsigned short* __restrict__ kb,
    const unsigned short* __restrict__ vb, unsigned short* __restrict__ ao) {
  __shared__ __align__(16) char smem[49152];   // Ks 16K | V dbuf 2x16K; epi 32K f32
  char* const Ks = smem;
  const int tid = threadIdx.x, lane = tid & 63, wv = tid >> 6;
  const int q31 = lane & 31, hi = lane >> 5;
  const int qtb = 7 - blockIdx.x;              // long blocks launch first
  const int h = blockIdx.y, b = blockIdx.z, kvh = h >> 2;
  const int q0 = qtb * 256;
  const int qrow = q0 + wv * 32 + q31;

  s8v qf[8];
  {
    const unsigned short* qp = qb + (size_t)(b * 2048 + qrow) * 4096 + h * 128 + hi * 8;
#pragma unroll
    for (int c = 0; c < 8; ++c) qf[c] = *(const s8v*)(qp + c * 16);
  }

  f16v oacc[4];
#pragma unroll
  for (int i = 0; i < 4; ++i) oacc[i] = (f16v)0.0f;
  float m_run = -3.0e38f, l_run = 0.0f;

  const unsigned short* ksrc[2]; char* kdst[2];
#pragma unroll
  for (int j = 0; j < 2; ++j) {
    const int r = wv * 8 + j * 4 + (lane >> 4);
    ksrc[j] = kb + (size_t)(b * 2048 + r) * 1024 + kvh * 128 + (((lane & 15) ^ (r & 15)) << 3);
    kdst[j] = Ks + (wv * 8 + j * 4) * 256;
  }
  const unsigned short* vsrc[2]; int vdoff[2];
#pragma unroll
  for (int j = 0; j < 2; ++j) {
    const int key = (wv * 2 + j) * 4 + ((lane & 7) >> 1);
    const int d = ((lane >> 3) & 7) * 16 + (lane & 1) * 8;
    vsrc[j] = vb + (size_t)(b * 2048 + key) * 1024 + kvh * 128 + d;
    vdoff[j] = (wv * 16 + j * 8) * 128;
  }

  const int ntiles = 4 * qtb + 4;
  const int my_qmax = q0 + wv * 32 + 31, wq_lo = q0 + wv * 32;

  GLDS16(ksrc[0], kdst[0]); GLDS16(ksrc[1], kdst[1]);
  GLDS16(vsrc[0], smem + 16384 + vdoff[0]); GLDS16(vsrc[1], smem + 16384 + vdoff[1]);
  asm volatile("s_waitcnt vmcnt(2)" ::: "memory");
  __builtin_amdgcn_sched_barrier(0);
  BAR;

  for (int t = 0; t < ntiles; ++t) {
    const int k0 = t * 64;
    const bool live = (k0 <= my_qmax);
    f16v s32a = (f16v)0.0f, s32b = (f16v)0.0f;
    if (live) {
      __builtin_amdgcn_s_setprio(1);
#pragma unroll
      for (int c = 0; c < 8; ++c) {
        const int sl = ((2 * c + hi) ^ (q31 & 15)) << 4;
        s8v kfa = *(const s8v*)(Ks + q31 * 256 + sl);
        s8v kfb = *(const s8v*)(Ks + (32 + q31) * 256 + sl);
        mfma3216(s32a, kfa, qf[c]);
        mfma3216(s32b, kfb, qf[c]);
      }
      __builtin_amdgcn_s_setprio(0);
      asm volatile("s_nop 7\n\ts_nop 7\n\ts_nop 7" : "+v"(s32a), "+v"(s32b));
    }
    BAR;
    {
      const size_t off = (size_t)((t + 1 < ntiles) ? t + 1 : t) * 65536;
      char* vbase = smem + 16384 + ((t + 1) & 1) * 16384;
      GLDS16(ksrc[0] + off, kdst[0]);
      GLDS16(ksrc[1] + off, kdst[1]);
      GLDS16(vsrc[0] + off, vbase + vdoff[0]);
      GLDS16(vsrc[1] + off, vbase + vdoff[1]);
    }
    asm volatile("s_waitcnt vmcnt(2)" ::: "memory");
    __builtin_amdgcn_sched_barrier(0);
    BAR;
    if (live) {
      const char* vbt = smem + 16384 + (t & 1) * 16384 + hi * 2048 +
                        ((lane >> 4) & 1) * 128 + ((lane & 15) << 3);
      s4v tA[8], tB[8];
#pragma unroll
      for (int u = 0; u < 8; ++u) tA[u] = tr_read(vbt, (u >> 1) * 256 + (u & 1) * 1024);

      float p[32];
#pragma unroll
      for (int r = 0; r < 16; ++r) { p[r] = s32a[r]; p[16 + r] = s32b[r]; }
      float tm = -3.0e38f;
      if (k0 + 64 <= wq_lo) {
#pragma unroll
        for (int j = 0; j < 32; ++j) { p[j] *= SCL_LOG2; tm = fmaxf(tm, p[j]); }
      } else {
#pragma unroll
        for (int j = 0; j < 32; ++j) {
          const int keyg = k0 + (j >> 4) * 32 + (j & 3) + 8 * ((j >> 2) & 3) + 4 * hi;
          p[j] = (keyg <= qrow) ? p[j] * SCL_LOG2 : -3.0e38f;
          tm = fmaxf(tm, p[j]);
        }
      }
      tm = fmaxf(tm, __shfl_xor(tm, 32));

      if (!__all(tm - m_run <= 8.0f)) {         // T13 defer-max
        const float m_new = fmaxf(m_run, tm);
        const float al = exp2f(m_run - m_new);
#pragma unroll
        for (int i = 0; i < 4; ++i)
#pragma unroll
          for (int r = 0; r < 16; ++r) oacc[i][r] *= al;
        l_run *= al;
        m_run = m_new;
      }
      float ps = 0.0f;
#pragma unroll
      for (int j = 0; j < 32; ++j) { p[j] = exp2f(p[j] - m_run); ps += p[j]; }
      ps += __shfl_xor(ps, 32);
      l_run += ps;

      s8v pf[4];
#pragma unroll
      for (int ks = 0; ks < 4; ++ks) {
        unsigned c0, c1, c2, c3;
        asm("v_cvt_pk_bf16_f32 %0, %1, %2" : "=v"(c0) : "v"(p[ks*8+0]), "v"(p[ks*8+1]));
        asm("v_cvt_pk_bf16_f32 %0, %1, %2" : "=v"(c1) : "v"(p[ks*8+2]), "v"(p[ks*8+3]));
        asm("v_cvt_pk_bf16_f32 %0, %1, %2" : "=v"(c2) : "v"(p[ks*8+4]), "v"(p[ks*8+5]));
        asm("v_cvt_pk_bf16_f32 %0, %1, %2" : "=v"(c3) : "v"(p[ks*8+6]), "v"(p[ks*8+7]));
        asm volatile("v_permlane32_swap_b32 %0, %1" : "+v"(c0), "+v"(c2));
        asm volatile("v_permlane32_swap_b32 %0, %1" : "+v"(c1), "+v"(c3));
        u4v pw; pw.x = c0; pw.y = c1; pw.z = c2; pw.w = c3;
        pf[ks] = __builtin_bit_cast(s8v, pw);
      }

#define PVS(KS, CUR, NXT, LAST) do { \
        if (!(LAST)) { \
          _Pragma("unroll") for (int u = 0; u < 8; ++u) \
            NXT[u] = tr_read(vbt, ((KS)+1)*4096 + (u >> 1) * 256 + (u & 1) * 1024); \
          asm volatile("s_waitcnt lgkmcnt(8)" ::: "memory"); \
        } else { asm volatile("s_waitcnt lgkmcnt(0)" ::: "memory"); } \
        __builtin_amdgcn_sched_barrier(0); \
        __builtin_amdgcn_s_setprio(1); \
        _Pragma("unroll") for (int dt = 0; dt < 4; ++dt) { \
          s8v vf = __builtin_shufflevector(CUR[dt*2], CUR[dt*2+1], 0,1,2,3,4,5,6,7); \
          mfma3216(oacc[dt], vf, pf[KS]); } \
        __builtin_amdgcn_s_setprio(0); \
      } while (0)
      PVS(0, tA, tB, 0);
      PVS(1, tB, tA, 0);
      PVS(2, tA, tB, 0);
      PVS(3, tB, tA, 1);
#undef PVS
    }
  }

  asm volatile("s_waitcnt vmcnt(0) lgkmcnt(0)" ::: "memory");
  asm volatile("s_nop 7\n\ts_nop 7\n\ts_nop 7" ::: "memory");
  __syncthreads();
  const float inv = 1.0f / l_run;
  float* Ost = (float*)smem;
  const int er = tid >> 3, ew = (tid & 7) * 16;
#pragma unroll
  for (int pq = 0; pq < 4; ++pq) {
    if ((wv >> 1) == pq) {
      const int qip = (wv & 1) * 32 + q31;
#pragma unroll
      for (int dt = 0; dt < 4; ++dt)
#pragma unroll
        for (int r = 0; r < 16; ++r) {
          const int d = dt * 32 + (r & 3) + 8 * ((r >> 2) & 3) + 4 * hi;
          Ost[qip * 128 + (d ^ ((qip & 7) << 2))] = oacc[dt][r] * inv;
        }
    }
    __syncthreads();
    const int sw = (er & 7) << 2;
    f4v a0 = *(const f4v*)(Ost + er * 128 + ((ew + 0) ^ sw));
    f4v a1 = *(const f4v*)(Ost + er * 128 + ((ew + 4) ^ sw));
    f4v a2 = *(const f4v*)(Ost + er * 128 + ((ew + 8) ^ sw));
    f4v a3 = *(const f4v*)(Ost + er * 128 + ((ew + 12) ^ sw));
    u4v r0, r1;
    r0.x = pk2(a0[0], a0[1]); r0.y = pk2(a0[2], a0[3]);
    r0.z = pk2(a1[0], a1[1]); r0.w = pk2(a1[2], a1[3]);
    r1.x = pk2(a2[0], a2[1]); r1.y = pk2(a2[2], a2[3]);
    r1.z = pk2(a3[0], a3[1]); r1.w = pk2(a3[2], a3[3]);
    unsigned short* dst = ao + (size_t)(b * 2048 + q0 + pq * 64 + er) * 4096 + h * 128 + ew;
    *(u4v*)dst = r0;
    *(u4v*)(dst + 8) = r1;
    __syncthreads();
  }
}

// ---------------------------------------------------------------------------
// Host launcher. Workspace layout (needs ws_size >= 268,435,456 B):
//   [0,32M)     xb bf16        [32M,80M)   wqkv bf16
//   [80M,112M)  wo bf16        [112M,208M) qkv bf16 partials C1|C2 (2x48M)
//                              (reused as attn_out bf16 after rope)
//   [208M,240M) q bf16         [240M,248M) k bf16    [248M,256M) v bf16
// ---------------------------------------------------------------------------
extern "C" void kernel_launch(void* const* d_in, const int* in_sizes, int n_in,
                              void* d_out, int out_size, void* d_ws, size_t ws_size,
                              hipStream_t stream) {
  (void)in_sizes; (void)n_in; (void)out_size; (void)ws_size;
  const float* x  = (const float*)d_in[0];
  const float* wq = (const float*)d_in[1];
  const float* wk = (const float*)d_in[2];
  const float* wv = (const float*)d_in[3];
  const float* wo = (const float*)d_in[4];
  const float* fr = (const float*)d_in[5];
  const float* fi = (const float*)d_in[6];

  float* out = (float*)d_out;
  float* xk  = out + 16777216;
  float* xv  = xk + 4194304;

  char* ws = (char*)d_ws;
  unsigned short* xb    = (unsigned short*)(ws);
  unsigned short* wqkvb = (unsigned short*)(ws + 33554432);
  unsigned short* wob   = (unsigned short*)(ws + 83886080);
  unsigned short* qkvb  = (unsigned short*)(ws + 117440512);  // C1|C2 bf16
  unsigned short* aob   = (unsigned short*)(ws + 117440512);  // reuse after rope
  unsigned short* qbuf  = (unsigned short*)(ws + 218103808);
  unsigned short* kbuf  = (unsigned short*)(ws + 251658240);
  unsigned short* vbuf  = (unsigned short*)(ws + 260046848);

  cvt_bf16<<<16384, 256, 0, stream>>>(x,  xb, 4194304);
  cvt_bf16<<<16384, 256, 0, stream>>>(wq, wqkvb, 4194304);
  cvt_bf16<<<4096,  256, 0, stream>>>(wk, wqkvb + 16777216, 1048576);
  cvt_bf16<<<4096,  256, 0, stream>>>(wv, wqkvb + 20971520, 1048576);
  cvt_bf16<<<16384, 256, 0, stream>>>(wo, wob, 4194304);

  // qkv: splitK (K halves of 2048), 768 blocks = 3 exact rounds on 256 CUs
  gemm_bt8<1><<<768, 512, 0, stream>>>(xb, wqkvb, qkvb, 4096, 6144, 4096, 2048, 384);
  rope_scatter<<<49152, 256, 0, stream>>>(qkvb, fr, fi, qbuf, kbuf, vbuf, xk, xv);
  attn_fwd<<<dim3(8, 32, 2), 512, 0, stream>>>(qbuf, kbuf, vbuf, aob);
  gemm_bt8<0><<<256, 512, 0, stream>>>(aob, wob, out, 4096, 4096, 4096, 4096, 256);
}

// Round 10
// 610.000 us; speedup vs baseline: 1.2792x; 1.0694x over previous
//
#include <hip/hip_runtime.h>
#include <hip/hip_bf16.h>

// ---------------------------------------------------------------------------
// Attention block: B=2 S=2048 D=4096 H=32 KV=8 HD=128 (GQA N_REP=4, causal)
// Pipeline: cvt -> GEMM8-splitK(qkv, bf16 partials) -> RoPE/sum/scatter
//           -> flash-attn(8w, 32x32 MFMA, q-tile 256) -> GEMM8(out)
// ---------------------------------------------------------------------------

typedef __attribute__((ext_vector_type(8)))  short s8v;   // 8 x bf16 (4 VGPR)
typedef __attribute__((ext_vector_type(4)))  short s4v;   // 4 x bf16 (2 VGPR)
typedef __attribute__((ext_vector_type(4)))  float f4v;
typedef __attribute__((ext_vector_type(16))) float f16v;  // 32x32 MFMA acc
typedef __attribute__((ext_vector_type(2)))  float f2v;
typedef __attribute__((ext_vector_type(2))) unsigned int u2v;
typedef __attribute__((ext_vector_type(4))) unsigned int u4v;

typedef __attribute__((address_space(3))) void lds_void;
typedef __attribute__((address_space(1))) void g_void;

#define GLDS16(gp, lp) __builtin_amdgcn_global_load_lds((g_void*)(gp), (lds_void*)(lp), 16, 0, 0)

__device__ __forceinline__ unsigned short f2b(float f) {  // f32 -> bf16 RNE
  unsigned u = __builtin_bit_cast(unsigned, f);
  u += 0x7fffu + ((u >> 16) & 1u);
  return (unsigned short)(u >> 16);
}
__device__ __forceinline__ unsigned pk2(float a, float b) {
  return (unsigned)f2b(a) | ((unsigned)f2b(b) << 16);
}
__device__ __forceinline__ float b2f(unsigned short h) {
  return __builtin_bit_cast(float, (unsigned)h << 16);
}

// inline-asm MFMAs (volatile; s_nop guards at every MFMA->VALU read-back)
__device__ __forceinline__ void mfma32(f4v& d, s8v a, s8v b) {
  asm volatile("v_mfma_f32_16x16x32_bf16 %0, %1, %2, %0" : "+v"(d) : "v"(a), "v"(b));
}
__device__ __forceinline__ void mfma3216(f16v& d, s8v a, s8v b) {
  asm volatile("v_mfma_f32_32x32x16_bf16 %0, %1, %2, %0" : "+v"(d) : "v"(a), "v"(b));
}
__device__ __forceinline__ s4v tr_read(const char* p, int imm) {
  s4v r;
  asm volatile("ds_read_b64_tr_b16 %0, %1 offset:%2"
               : "=v"(r) : "v"((lds_void*)p), "n"(imm));
  return r;
}

// ---------------------------------------------------------------------------
// f32 -> bf16 convert
// ---------------------------------------------------------------------------
__global__ __launch_bounds__(256) void cvt_bf16(const float* __restrict__ s,
                                                unsigned short* __restrict__ d, int n4) {
  const int i = blockIdx.x * 256 + threadIdx.x;
  if (i >= n4) return;
  f4v v = *(const f4v*)(s + (size_t)i * 4);
  u2v r;
  r.x = pk2(v[0], v[1]);
  r.y = pk2(v[2], v[3]);
  *(u2v*)(d + (size_t)i * 4) = r;
}

// ---------------------------------------------------------------------------
// 8-phase GEMM, C = A[M][Ks] * B[N][Ks]^T over K range [kOff, kOff+Klen).
// 256x256 tile, BK=64, 512 thr = 8 waves (2M x 4N), 128 KiB LDS double-buffer.
// Round-10 schedule v3: quadrant order (0,0),(0,1),(1,0),(1,1) so B's LDS
// reads finish at ph1 and A's at ph2 -> stage slots ph2: t+2.B0+B1 (4 loads),
// ph3: t+2.A0+A1 (4 loads) + vmcnt(8) gate; ONE barrier per phase (closing) —
// STG(p) vs last-reader(p-1) is ordered by BAR(p-1) (each wave's own
// lgkmcnt(0) drain precedes its barrier arrival); MFMA needs only own-wave
// lgkmcnt; gates keep gate->barrier pairing. Tail clamp stages dead regions.
// ---------------------------------------------------------------------------
#define BAR      asm volatile("s_barrier" ::: "memory")
#define WLGKM    do { asm volatile("s_waitcnt lgkmcnt(0)" ::: "memory"); \
                      __builtin_amdgcn_sched_barrier(0); } while (0)
#define WVM8     do { asm volatile("s_waitcnt vmcnt(8)" ::: "memory"); \
                      __builtin_amdgcn_sched_barrier(0); } while (0)

template <int OUTB>
__global__ __launch_bounds__(512, 2) void gemm_bt8(const unsigned short* __restrict__ A,
                                                   const unsigned short* __restrict__ Bp,
                                                   void* __restrict__ Cout,
                                                   int M, int N, int Ks, int Klen,
                                                   int nTiles) {
  __shared__ __align__(16) char smem[131072];
  const int tid = threadIdx.x, lane = tid & 63, wv = tid >> 6;
  const int qi = lane & 15, g = lane >> 4;
  const int wm = wv >> 2, wn = wv & 3;

  const int nwg = gridDim.x, cpx = nwg >> 3;
  const int id = blockIdx.x;
  const int swz = (id & 7) * cpx + (id >> 3);
  const int half = swz / nTiles;
  const int tile = swz - half * nTiles;
  const int kOff = half * Klen;
  const int MT = M >> 8;
  const int m0 = (tile % MT) * 256, n0 = (tile / MT) * 256;
  const int NT = Klen >> 6;

  const int srowo = wv * 8 + (lane >> 3);
  const int scole = ((lane & 7) ^ (lane >> 3)) << 3;
  const size_t rA = (size_t)(m0 + srowo) * Ks + kOff + scole;
  const size_t rB = (size_t)(n0 + srowo) * Ks + kOff + scole;
  char* sdA = smem + wv * 1024;
  char* sdB = smem + 32768 + wv * 1024;

#define STG_A(D, H, KT) do { \
    GLDS16(A + rA + (size_t)((H)*128) * Ks + (size_t)(KT)*64,      sdA + (D)*65536 + (H)*16384); \
    GLDS16(A + rA + (size_t)((H)*128 + 64) * Ks + (size_t)(KT)*64, sdA + (D)*65536 + (H)*16384 + 8192); } while (0)
#define STG_B(D, H, KT) do { \
    GLDS16(Bp + rB + (size_t)((H)*128) * Ks + (size_t)(KT)*64,      sdB + (D)*65536 + (H)*16384); \
    GLDS16(Bp + rB + (size_t)((H)*128 + 64) * Ks + (size_t)(KT)*64, sdB + (D)*65536 + (H)*16384 + 8192); } while (0)

  const int sw = (qi & 7) << 4;
  const char* frA = smem + (wm * 128 + qi) * 128;
  const char* frB = smem + 32768 + (wn * 64 + qi) * 128;

#define RDA4(D, F0) do { _Pragma("unroll") for (int f_ = 0; f_ < 4; ++f_) \
    _Pragma("unroll") for (int k_ = 0; k_ < 2; ++k_) \
      a[(F0) + f_][k_] = *(const s8v*)(frA + (D)*65536 + ((F0) + f_) * 2048 + (((k_ << 6) + (g << 4)) ^ sw)); } while (0)
#define RDB2(D, N0) do { _Pragma("unroll") for (int n_ = 0; n_ < 2; ++n_) \
    _Pragma("unroll") for (int k_ = 0; k_ < 2; ++k_) \
      b[(N0) + n_][k_] = *(const s8v*)(frB + (D)*65536 + ((N0) + n_) * 2048 + (((k_ << 6) + (g << 4)) ^ sw)); } while (0)
#define MQUAD(F0, N0) do { __builtin_amdgcn_s_setprio(1); \
    _Pragma("unroll") for (int f_ = 0; f_ < 4; ++f_) \
    _Pragma("unroll") for (int n_ = 0; n_ < 2; ++n_) \
    _Pragma("unroll") for (int k_ = 0; k_ < 2; ++k_) \
      mfma32(acc[(F0) + f_][(N0) + n_], a[(F0) + f_][k_], b[(N0) + n_][k_]); \
    __builtin_amdgcn_s_setprio(0); } while (0)

  f4v acc[8][4];
#pragma unroll
  for (int i = 0; i < 8; ++i)
#pragma unroll
    for (int j = 0; j < 4; ++j) acc[i][j] = (f4v)0.0f;

  // prologue: tile0 (8 loads) + tile1 (8 loads); drain tile0, keep tile1 flying
  STG_A(0, 0, 0); STG_A(0, 1, 0); STG_B(0, 0, 0); STG_B(0, 1, 0);
  STG_A(1, 0, 1); STG_A(1, 1, 1); STG_B(1, 0, 1); STG_B(1, 1, 1);
  WVM8;
  BAR;

  s8v a[8][2], b[4][2];
#pragma unroll 1
  for (int it = 0; it < NT / 2; ++it) {
    const int t = 2 * it;
    const int k2 = (t + 2 < NT) ? t + 2 : NT - 1;   // clamped: dest dead on tail
    const int k3 = (t + 3 < NT) ? t + 3 : NT - 1;
    // ---- phase 0: buf0 quad(0,0)
    RDA4(0, 0); RDB2(0, 0);
    WLGKM; MQUAD(0, 0); BAR;
    // ---- phase 1: buf0 quad(0,1)  (a0-3 carried)
    RDB2(0, 2);
    WLGKM; MQUAD(0, 2); BAR;
    // ---- phase 2: buf0 quad(1,0); stage t+2.B (buf0.B last read ph1)
    RDA4(0, 4);
    STG_B(0, 0, k2); STG_B(0, 1, k2);
    WLGKM; MQUAD(4, 0); BAR;
    // ---- phase 3: buf0 quad(1,1); stage t+2.A (buf0.A last read ph2); gate
    STG_A(0, 0, k2); STG_A(0, 1, k2);
    MQUAD(4, 2);
    WVM8; BAR;
    // ---- phase 4: buf1 quad(0,0)
    RDA4(1, 0); RDB2(1, 0);
    WLGKM; MQUAD(0, 0); BAR;
    // ---- phase 5: buf1 quad(0,1)
    RDB2(1, 2);
    WLGKM; MQUAD(0, 2); BAR;
    // ---- phase 6: buf1 quad(1,0); stage t+3.B
    RDA4(1, 4);
    STG_B(1, 0, k3); STG_B(1, 1, k3);
    WLGKM; MQUAD(4, 0); BAR;
    // ---- phase 7: buf1 quad(1,1); stage t+3.A; gate
    STG_A(1, 0, k3); STG_A(1, 1, k3);
    MQUAD(4, 2);
    WVM8; BAR;
  }

  asm volatile("s_waitcnt vmcnt(0)" ::: "memory");
  asm volatile("s_nop 7\n\ts_nop 7" ::: "memory");   // MFMA->VALU hazard guard
  const int r4 = g * 4;
  if (OUTB) {
    unsigned short* Cb = (unsigned short*)Cout + (size_t)half * M * N;
#pragma unroll
    for (int fm = 0; fm < 8; ++fm)
#pragma unroll
      for (int fn = 0; fn < 4; ++fn)
#pragma unroll
        for (int r = 0; r < 4; ++r)
          Cb[(size_t)(m0 + wm * 128 + fm * 16 + r4 + r) * N + (n0 + wn * 64 + fn * 16 + qi)] =
              f2b(acc[fm][fn][r]);
  } else {
    float* Cf = (float*)Cout;
#pragma unroll
    for (int fm = 0; fm < 8; ++fm)
#pragma unroll
      for (int fn = 0; fn < 4; ++fn)
#pragma unroll
        for (int r = 0; r < 4; ++r)
          Cf[(size_t)(m0 + wm * 128 + fm * 16 + r4 + r) * N + (n0 + wn * 64 + fn * 16 + qi)] =
              acc[fm][fn][r];
  }
}

// ---------------------------------------------------------------------------
// RoPE + splitK-sum + scatter (unchanged)
// ---------------------------------------------------------------------------
__global__ __launch_bounds__(256) void rope_scatter(
    const unsigned short* __restrict__ qkvp, const float* __restrict__ fr,
    const float* __restrict__ fi,
    unsigned short* __restrict__ qb, unsigned short* __restrict__ kb,
    unsigned short* __restrict__ vbuf, float* __restrict__ xk, float* __restrict__ xv) {
  const int idx = blockIdx.x * 256 + threadIdx.x;
  const int token = idx / 3072;
  const int col2  = (idx - token * 3072) * 2;
  const int pos   = token & 2047;
  const unsigned u1 = *(const unsigned*)(qkvp + (size_t)token * 6144 + col2);
  const unsigned u2 = *(const unsigned*)(qkvp + 25165824u + (size_t)token * 6144 + col2);
  float v0 = b2f((unsigned short)u1) + b2f((unsigned short)u2);
  float v1 = b2f((unsigned short)(u1 >> 16)) + b2f((unsigned short)(u2 >> 16));
  if (col2 < 4096) {
    const int j = (col2 & 127) >> 1;
    const float cr = fr[pos * 64 + j], ci = fi[pos * 64 + j];
    const float a = v0 * cr - ci * v1;
    const float o = v0 * ci + v1 * cr;
    *(unsigned*)(qb + (size_t)token * 4096 + col2) = pk2(a, o);
  } else if (col2 < 5120) {
    const int lc = col2 - 4096;
    const int j = (lc & 127) >> 1;
    const float cr = fr[pos * 64 + j], ci = fi[pos * 64 + j];
    const float a = v0 * cr - ci * v1;
    const float o = v0 * ci + v1 * cr;
    *(unsigned*)(kb + (size_t)token * 1024 + lc) = pk2(a, o);
    f2v w; w.x = a; w.y = o;
    *(f2v*)(xk + (size_t)token * 1024 + lc) = w;
  } else {
    const int lc = col2 - 5120;
    *(unsigned*)(vbuf + (size_t)token * 1024 + lc) = pk2(v0, v1);
    f2v w; w.x = v0; w.y = v1;
    *(f2v*)(xv + (size_t)token * 1024 + lc) = w;
  }
}

// ---------------------------------------------------------------------------
// Causal GQA flash attention — 8 waves x 32 q-rows (q-tile 256), 32x32x16
// MFMA, KVBLK=64 (unchanged from round 8, proven).
// ---------------------------------------------------------------------------
#define SCL_LOG2 0.12751744f   // (1/sqrt(128)) * log2(e)

__global__ __launch_bounds__(512, 2) void attn_fwd(
    const unsigned short* __restrict__ qb, const unsigned short* __restrict__ kb,
    const unsigned short* __restrict__ vb, unsigned short* __restrict__ ao) {
  __shared__ __align__(16) char smem[49152];   // Ks 16K | V dbuf 2x16K; epi 32K f32
  char* const Ks = smem;
  const int tid = threadIdx.x, lane = tid & 63, wv = tid >> 6;
  const int q31 = lane & 31, hi = lane >> 5;
  const int qtb = 7 - blockIdx.x;              // long blocks launch first
  const int h = blockIdx.y, b = blockIdx.z, kvh = h >> 2;
  const int q0 = qtb * 256;
  const int qrow = q0 + wv * 32 + q31;

  s8v qf[8];
  {
    const unsigned short* qp = qb + (size_t)(b * 2048 + qrow) * 4096 + h * 128 + hi * 8;
#pragma unroll
    for (int c = 0; c < 8; ++c) qf[c] = *(const s8v*)(qp + c * 16);
  }

  f16v oacc[4];
#pragma unroll
  for (int i = 0; i < 4; ++i) oacc[i] = (f16v)0.0f;
  float m_run = -3.0e38f, l_run = 0.0f;

  const unsigned short* ksrc[2]; char* kdst[2];
#pragma unroll
  for (int j = 0; j < 2; ++j) {
    const int r = wv * 8 + j * 4 + (lane >> 4);
    ksrc[j] = kb + (size_t)(b * 2048 + r) * 1024 + kvh * 128 + (((lane & 15) ^ (r & 15)) << 3);
    kdst[j] = Ks + (wv * 8 + j * 4) * 256;
  }
  const unsigned short* vsrc[2]; int vdoff[2];
#pragma unroll
  for (int j = 0; j < 2; ++j) {
    const int key = (wv * 2 + j) * 4 + ((lane & 7) >> 1);
    const int d = ((lane >> 3) & 7) * 16 + (lane & 1) * 8;
    vsrc[j] = vb + (size_t)(b * 2048 + key) * 1024 + kvh * 128 + d;
    vdoff[j] = (wv * 16 + j * 8) * 128;
  }

  const int ntiles = 4 * qtb + 4;
  const int my_qmax = q0 + wv * 32 + 31, wq_lo = q0 + wv * 32;

  GLDS16(ksrc[0], kdst[0]); GLDS16(ksrc[1], kdst[1]);
  GLDS16(vsrc[0], smem + 16384 + vdoff[0]); GLDS16(vsrc[1], smem + 16384 + vdoff[1]);
  asm volatile("s_waitcnt vmcnt(2)" ::: "memory");
  __builtin_amdgcn_sched_barrier(0);
  BAR;

  for (int t = 0; t < ntiles; ++t) {
    const int k0 = t * 64;
    const bool live = (k0 <= my_qmax);
    f16v s32a = (f16v)0.0f, s32b = (f16v)0.0f;
    if (live) {
      __builtin_amdgcn_s_setprio(1);
#pragma unroll
      for (int c = 0; c < 8; ++c) {
        const int sl = ((2 * c + hi) ^ (q31 & 15)) << 4;
        s8v kfa = *(const s8v*)(Ks + q31 * 256 + sl);
        s8v kfb = *(const s8v*)(Ks + (32 + q31) * 256 + sl);
        mfma3216(s32a, kfa, qf[c]);
        mfma3216(s32b, kfb, qf[c]);
      }
      __builtin_amdgcn_s_setprio(0);
      asm volatile("s_nop 7\n\ts_nop 7\n\ts_nop 7" : "+v"(s32a), "+v"(s32b));
    }
    BAR;
    {
      const size_t off = (size_t)((t + 1 < ntiles) ? t + 1 : t) * 65536;
      char* vbase = smem + 16384 + ((t + 1) & 1) * 16384;
      GLDS16(ksrc[0] + off, kdst[0]);
      GLDS16(ksrc[1] + off, kdst[1]);
      GLDS16(vsrc[0] + off, vbase + vdoff[0]);
      GLDS16(vsrc[1] + off, vbase + vdoff[1]);
    }
    asm volatile("s_waitcnt vmcnt(2)" ::: "memory");
    __builtin_amdgcn_sched_barrier(0);
    BAR;
    if (live) {
      const char* vbt = smem + 16384 + (t & 1) * 16384 + hi * 2048 +
                        ((lane >> 4) & 1) * 128 + ((lane & 15) << 3);
      s4v tA[8], tB[8];
#pragma unroll
      for (int u = 0; u < 8; ++u) tA[u] = tr_read(vbt, (u >> 1) * 256 + (u & 1) * 1024);

      float p[32];
#pragma unroll
      for (int r = 0; r < 16; ++r) { p[r] = s32a[r]; p[16 + r] = s32b[r]; }
      float tm = -3.0e38f;
      if (k0 + 64 <= wq_lo) {
#pragma unroll
        for (int j = 0; j < 32; ++j) { p[j] *= SCL_LOG2; tm = fmaxf(tm, p[j]); }
      } else {
#pragma unroll
        for (int j = 0; j < 32; ++j) {
          const int keyg = k0 + (j >> 4) * 32 + (j & 3) + 8 * ((j >> 2) & 3) + 4 * hi;
          p[j] = (keyg <= qrow) ? p[j] * SCL_LOG2 : -3.0e38f;
          tm = fmaxf(tm, p[j]);
        }
      }
      tm = fmaxf(tm, __shfl_xor(tm, 32));

      if (!__all(tm - m_run <= 8.0f)) {         // T13 defer-max
        const float m_new = fmaxf(m_run, tm);
        const float al = exp2f(m_run - m_new);
#pragma unroll
        for (int i = 0; i < 4; ++i)
#pragma unroll
          for (int r = 0; r < 16; ++r) oacc[i][r] *= al;
        l_run *= al;
        m_run = m_new;
      }
      float ps = 0.0f;
#pragma unroll
      for (int j = 0; j < 32; ++j) { p[j] = exp2f(p[j] - m_run); ps += p[j]; }
      ps += __shfl_xor(ps, 32);
      l_run += ps;

      s8v pf[4];
#pragma unroll
      for (int ks = 0; ks < 4; ++ks) {
        unsigned c0, c1, c2, c3;
        asm("v_cvt_pk_bf16_f32 %0, %1, %2" : "=v"(c0) : "v"(p[ks*8+0]), "v"(p[ks*8+1]));
        asm("v_cvt_pk_bf16_f32 %0, %1, %2" : "=v"(c1) : "v"(p[ks*8+2]), "v"(p[ks*8+3]));
        asm("v_cvt_pk_bf16_f32 %0, %1, %2" : "=v"(c2) : "v"(p[ks*8+4]), "v"(p[ks*8+5]));
        asm("v_cvt_pk_bf16_f32 %0, %1, %2" : "=v"(c3) : "v"(p[ks*8+6]), "v"(p[ks*8+7]));
        asm volatile("v_permlane32_swap_b32 %0, %1" : "+v"(c0), "+v"(c2));
        asm volatile("v_permlane32_swap_b32 %0, %1" : "+v"(c1), "+v"(c3));
        u4v pw; pw.x = c0; pw.y = c1; pw.z = c2; pw.w = c3;
        pf[ks] = __builtin_bit_cast(s8v, pw);
      }

#define PVS(KS, CUR, NXT, LAST) do { \
        if (!(LAST)) { \
          _Pragma("unroll") for (int u = 0; u < 8; ++u) \
            NXT[u] = tr_read(vbt, ((KS)+1)*4096 + (u >> 1) * 256 + (u & 1) * 1024); \
          asm volatile("s_waitcnt lgkmcnt(8)" ::: "memory"); \
        } else { asm volatile("s_waitcnt lgkmcnt(0)" ::: "memory"); } \
        __builtin_amdgcn_sched_barrier(0); \
        __builtin_amdgcn_s_setprio(1); \
        _Pragma("unroll") for (int dt = 0; dt < 4; ++dt) { \
          s8v vf = __builtin_shufflevector(CUR[dt*2], CUR[dt*2+1], 0,1,2,3,4,5,6,7); \
          mfma3216(oacc[dt], vf, pf[KS]); } \
        __builtin_amdgcn_s_setprio(0); \
      } while (0)
      PVS(0, tA, tB, 0);
      PVS(1, tB, tA, 0);
      PVS(2, tA, tB, 0);
      PVS(3, tB, tA, 1);
#undef PVS
    }
  }

  asm volatile("s_waitcnt vmcnt(0) lgkmcnt(0)" ::: "memory");
  asm volatile("s_nop 7\n\ts_nop 7\n\ts_nop 7" ::: "memory");
  __syncthreads();
  const float inv = 1.0f / l_run;
  float* Ost = (float*)smem;
  const int er = tid >> 3, ew = (tid & 7) * 16;
#pragma unroll
  for (int pq = 0; pq < 4; ++pq) {
    if ((wv >> 1) == pq) {
      const int qip = (wv & 1) * 32 + q31;
#pragma unroll
      for (int dt = 0; dt < 4; ++dt)
#pragma unroll
        for (int r = 0; r < 16; ++r) {
          const int d = dt * 32 + (r & 3) + 8 * ((r >> 2) & 3) + 4 * hi;
          Ost[qip * 128 + (d ^ ((qip & 7) << 2))] = oacc[dt][r] * inv;
        }
    }
    __syncthreads();
    const int sw = (er & 7) << 2;
    f4v a0 = *(const f4v*)(Ost + er * 128 + ((ew + 0) ^ sw));
    f4v a1 = *(const f4v*)(Ost + er * 128 + ((ew + 4) ^ sw));
    f4v a2 = *(const f4v*)(Ost + er * 128 + ((ew + 8) ^ sw));
    f4v a3 = *(const f4v*)(Ost + er * 128 + ((ew + 12) ^ sw));
    u4v r0, r1;
    r0.x = pk2(a0[0], a0[1]); r0.y = pk2(a0[2], a0[3]);
    r0.z = pk2(a1[0], a1[1]); r0.w = pk2(a1[2], a1[3]);
    r1.x = pk2(a2[0], a2[1]); r1.y = pk2(a2[2], a2[3]);
    r1.z = pk2(a3[0], a3[1]); r1.w = pk2(a3[2], a3[3]);
    unsigned short* dst = ao + (size_t)(b * 2048 + q0 + pq * 64 + er) * 4096 + h * 128 + ew;
    *(u4v*)dst = r0;
    *(u4v*)(dst + 8) = r1;
    __syncthreads();
  }
}

// ---------------------------------------------------------------------------
// Host launcher. Workspace layout (needs ws_size >= 268,435,456 B):
//   [0,32M)     xb bf16        [32M,80M)   wqkv bf16
//   [80M,112M)  wo bf16        [112M,208M) qkv bf16 partials C1|C2 (2x48M)
//                              (reused as attn_out bf16 after rope)
//   [208M,240M) q bf16         [240M,248M) k bf16    [248M,256M) v bf16
// ---------------------------------------------------------------------------
extern "C" void kernel_launch(void* const* d_in, const int* in_sizes, int n_in,
                              void* d_out, int out_size, void* d_ws, size_t ws_size,
                              hipStream_t stream) {
  (void)in_sizes; (void)n_in; (void)out_size; (void)ws_size;
  const float* x  = (const float*)d_in[0];
  const float* wq = (const float*)d_in[1];
  const float* wk = (const float*)d_in[2];
  const float* wv = (const float*)d_in[3];
  const float* wo = (const float*)d_in[4];
  const float* fr = (const float*)d_in[5];
  const float* fi = (const float*)d_in[6];

  float* out = (float*)d_out;
  float* xk  = out + 16777216;
  float* xv  = xk + 4194304;

  char* ws = (char*)d_ws;
  unsigned short* xb    = (unsigned short*)(ws);
  unsigned short* wqkvb = (unsigned short*)(ws + 33554432);
  unsigned short* wob   = (unsigned short*)(ws + 83886080);
  unsigned short* qkvb  = (unsigned short*)(ws + 117440512);  // C1|C2 bf16
  unsigned short* aob   = (unsigned short*)(ws + 117440512);  // reuse after rope
  unsigned short* qbuf  = (unsigned short*)(ws + 218103808);
  unsigned short* kbuf  = (unsigned short*)(ws + 251658240);
  unsigned short* vbuf  = (unsigned short*)(ws + 260046848);

  cvt_bf16<<<16384, 256, 0, stream>>>(x,  xb, 4194304);
  cvt_bf16<<<16384, 256, 0, stream>>>(wq, wqkvb, 4194304);
  cvt_bf16<<<4096,  256, 0, stream>>>(wk, wqkvb + 16777216, 1048576);
  cvt_bf16<<<4096,  256, 0, stream>>>(wv, wqkvb + 20971520, 1048576);
  cvt_bf16<<<16384, 256, 0, stream>>>(wo, wob, 4194304);

  // qkv: splitK (K halves of 2048), 768 blocks = 3 exact rounds on 256 CUs
  gemm_bt8<1><<<768, 512, 0, stream>>>(xb, wqkvb, qkvb, 4096, 6144, 4096, 2048, 384);
  rope_scatter<<<49152, 256, 0, stream>>>(qkvb, fr, fi, qbuf, kbuf, vbuf, xk, xv);
  attn_fwd<<<dim3(8, 32, 2), 512, 0, stream>>>(qbuf, kbuf, vbuf, aob);
  gemm_bt8<0><<<256, 512, 0, stream>>>(aob, wob, out, 4096, 4096, 4096, 4096, 256);
}

// Round 11
// 590.263 us; speedup vs baseline: 1.3220x; 1.0334x over previous
//
#include <hip/hip_runtime.h>
#include <hip/hip_bf16.h>

// ---------------------------------------------------------------------------
// Attention block: B=2 S=2048 D=4096 H=32 KV=8 HD=128 (GQA N_REP=4, causal)
// Pipeline: cvt -> GEMM8-splitK(qkv, bf16 partials) -> RoPE/sum/scatter
//           -> flash-attn(8w, 32x32 MFMA, q-tile 256, K+V dbuf) -> GEMM8(out)
// ---------------------------------------------------------------------------

typedef __attribute__((ext_vector_type(8)))  short s8v;   // 8 x bf16 (4 VGPR)
typedef __attribute__((ext_vector_type(4)))  short s4v;   // 4 x bf16 (2 VGPR)
typedef __attribute__((ext_vector_type(4)))  float f4v;
typedef __attribute__((ext_vector_type(16))) float f16v;  // 32x32 MFMA acc
typedef __attribute__((ext_vector_type(2)))  float f2v;
typedef __attribute__((ext_vector_type(2))) unsigned int u2v;
typedef __attribute__((ext_vector_type(4))) unsigned int u4v;

typedef __attribute__((address_space(3))) void lds_void;
typedef __attribute__((address_space(1))) void g_void;

#define GLDS16(gp, lp) __builtin_amdgcn_global_load_lds((g_void*)(gp), (lds_void*)(lp), 16, 0, 0)

#define SCL_LOG2 0.12751744f   // (1/sqrt(128)) * log2(e); pre-folded into Q at rope

__device__ __forceinline__ unsigned short f2b(float f) {  // f32 -> bf16 RNE
  unsigned u = __builtin_bit_cast(unsigned, f);
  u += 0x7fffu + ((u >> 16) & 1u);
  return (unsigned short)(u >> 16);
}
__device__ __forceinline__ unsigned pk2(float a, float b) {
  return (unsigned)f2b(a) | ((unsigned)f2b(b) << 16);
}
__device__ __forceinline__ float b2f(unsigned short h) {
  return __builtin_bit_cast(float, (unsigned)h << 16);
}

// inline-asm MFMAs (volatile; s_nop guards at every MFMA->VALU read-back)
__device__ __forceinline__ void mfma32(f4v& d, s8v a, s8v b) {
  asm volatile("v_mfma_f32_16x16x32_bf16 %0, %1, %2, %0" : "+v"(d) : "v"(a), "v"(b));
}
__device__ __forceinline__ void mfma3216(f16v& d, s8v a, s8v b) {
  asm volatile("v_mfma_f32_32x32x16_bf16 %0, %1, %2, %0" : "+v"(d) : "v"(a), "v"(b));
}
__device__ __forceinline__ s4v tr_read(const char* p, int imm) {
  s4v r;
  asm volatile("ds_read_b64_tr_b16 %0, %1 offset:%2"
               : "=v"(r) : "v"((lds_void*)p), "n"(imm));
  return r;
}

// ---------------------------------------------------------------------------
// f32 -> bf16 convert
// ---------------------------------------------------------------------------
__global__ __launch_bounds__(256) void cvt_bf16(const float* __restrict__ s,
                                                unsigned short* __restrict__ d, int n4) {
  const int i = blockIdx.x * 256 + threadIdx.x;
  if (i >= n4) return;
  f4v v = *(const f4v*)(s + (size_t)i * 4);
  u2v r;
  r.x = pk2(v[0], v[1]);
  r.y = pk2(v[2], v[3]);
  *(u2v*)(d + (size_t)i * 4) = r;
}

// ---------------------------------------------------------------------------
// 8-phase GEMM (unchanged from round 10 — schedule v3, proven)
// ---------------------------------------------------------------------------
#define BAR      asm volatile("s_barrier" ::: "memory")
#define WLGKM    do { asm volatile("s_waitcnt lgkmcnt(0)" ::: "memory"); \
                      __builtin_amdgcn_sched_barrier(0); } while (0)
#define WVM8     do { asm volatile("s_waitcnt vmcnt(8)" ::: "memory"); \
                      __builtin_amdgcn_sched_barrier(0); } while (0)

template <int OUTB>
__global__ __launch_bounds__(512, 2) void gemm_bt8(const unsigned short* __restrict__ A,
                                                   const unsigned short* __restrict__ Bp,
                                                   void* __restrict__ Cout,
                                                   int M, int N, int Ks, int Klen,
                                                   int nTiles) {
  __shared__ __align__(16) char smem[131072];
  const int tid = threadIdx.x, lane = tid & 63, wv = tid >> 6;
  const int qi = lane & 15, g = lane >> 4;
  const int wm = wv >> 2, wn = wv & 3;

  const int nwg = gridDim.x, cpx = nwg >> 3;
  const int id = blockIdx.x;
  const int swz = (id & 7) * cpx + (id >> 3);
  const int half = swz / nTiles;
  const int tile = swz - half * nTiles;
  const int kOff = half * Klen;
  const int MT = M >> 8;
  const int m0 = (tile % MT) * 256, n0 = (tile / MT) * 256;
  const int NT = Klen >> 6;

  const int srowo = wv * 8 + (lane >> 3);
  const int scole = ((lane & 7) ^ (lane >> 3)) << 3;
  const size_t rA = (size_t)(m0 + srowo) * Ks + kOff + scole;
  const size_t rB = (size_t)(n0 + srowo) * Ks + kOff + scole;
  char* sdA = smem + wv * 1024;
  char* sdB = smem + 32768 + wv * 1024;

#define STG_A(D, H, KT) do { \
    GLDS16(A + rA + (size_t)((H)*128) * Ks + (size_t)(KT)*64,      sdA + (D)*65536 + (H)*16384); \
    GLDS16(A + rA + (size_t)((H)*128 + 64) * Ks + (size_t)(KT)*64, sdA + (D)*65536 + (H)*16384 + 8192); } while (0)
#define STG_B(D, H, KT) do { \
    GLDS16(Bp + rB + (size_t)((H)*128) * Ks + (size_t)(KT)*64,      sdB + (D)*65536 + (H)*16384); \
    GLDS16(Bp + rB + (size_t)((H)*128 + 64) * Ks + (size_t)(KT)*64, sdB + (D)*65536 + (H)*16384 + 8192); } while (0)

  const int sw = (qi & 7) << 4;
  const char* frA = smem + (wm * 128 + qi) * 128;
  const char* frB = smem + 32768 + (wn * 64 + qi) * 128;

#define RDA4(D, F0) do { _Pragma("unroll") for (int f_ = 0; f_ < 4; ++f_) \
    _Pragma("unroll") for (int k_ = 0; k_ < 2; ++k_) \
      a[(F0) + f_][k_] = *(const s8v*)(frA + (D)*65536 + ((F0) + f_) * 2048 + (((k_ << 6) + (g << 4)) ^ sw)); } while (0)
#define RDB2(D, N0) do { _Pragma("unroll") for (int n_ = 0; n_ < 2; ++n_) \
    _Pragma("unroll") for (int k_ = 0; k_ < 2; ++k_) \
      b[(N0) + n_][k_] = *(const s8v*)(frB + (D)*65536 + ((N0) + n_) * 2048 + (((k_ << 6) + (g << 4)) ^ sw)); } while (0)
#define MQUAD(F0, N0) do { __builtin_amdgcn_s_setprio(1); \
    _Pragma("unroll") for (int f_ = 0; f_ < 4; ++f_) \
    _Pragma("unroll") for (int n_ = 0; n_ < 2; ++n_) \
    _Pragma("unroll") for (int k_ = 0; k_ < 2; ++k_) \
      mfma32(acc[(F0) + f_][(N0) + n_], a[(F0) + f_][k_], b[(N0) + n_][k_]); \
    __builtin_amdgcn_s_setprio(0); } while (0)

  f4v acc[8][4];
#pragma unroll
  for (int i = 0; i < 8; ++i)
#pragma unroll
    for (int j = 0; j < 4; ++j) acc[i][j] = (f4v)0.0f;

  STG_A(0, 0, 0); STG_A(0, 1, 0); STG_B(0, 0, 0); STG_B(0, 1, 0);
  STG_A(1, 0, 1); STG_A(1, 1, 1); STG_B(1, 0, 1); STG_B(1, 1, 1);
  WVM8;
  BAR;

  s8v a[8][2], b[4][2];
#pragma unroll 1
  for (int it = 0; it < NT / 2; ++it) {
    const int t = 2 * it;
    const int k2 = (t + 2 < NT) ? t + 2 : NT - 1;
    const int k3 = (t + 3 < NT) ? t + 3 : NT - 1;
    RDA4(0, 0); RDB2(0, 0);
    WLGKM; MQUAD(0, 0); BAR;
    RDB2(0, 2);
    WLGKM; MQUAD(0, 2); BAR;
    RDA4(0, 4);
    STG_B(0, 0, k2); STG_B(0, 1, k2);
    WLGKM; MQUAD(4, 0); BAR;
    STG_A(0, 0, k2); STG_A(0, 1, k2);
    MQUAD(4, 2);
    WVM8; BAR;
    RDA4(1, 0); RDB2(1, 0);
    WLGKM; MQUAD(0, 0); BAR;
    RDB2(1, 2);
    WLGKM; MQUAD(0, 2); BAR;
    RDA4(1, 4);
    STG_B(1, 0, k3); STG_B(1, 1, k3);
    WLGKM; MQUAD(4, 0); BAR;
    STG_A(1, 0, k3); STG_A(1, 1, k3);
    MQUAD(4, 2);
    WVM8; BAR;
  }

  asm volatile("s_waitcnt vmcnt(0)" ::: "memory");
  asm volatile("s_nop 7\n\ts_nop 7" ::: "memory");
  const int r4 = g * 4;
  if (OUTB) {
    unsigned short* Cb = (unsigned short*)Cout + (size_t)half * M * N;
#pragma unroll
    for (int fm = 0; fm < 8; ++fm)
#pragma unroll
      for (int fn = 0; fn < 4; ++fn)
#pragma unroll
        for (int r = 0; r < 4; ++r)
          Cb[(size_t)(m0 + wm * 128 + fm * 16 + r4 + r) * N + (n0 + wn * 64 + fn * 16 + qi)] =
              f2b(acc[fm][fn][r]);
  } else {
    float* Cf = (float*)Cout;
#pragma unroll
    for (int fm = 0; fm < 8; ++fm)
#pragma unroll
      for (int fn = 0; fn < 4; ++fn)
#pragma unroll
        for (int r = 0; r < 4; ++r)
          Cf[(size_t)(m0 + wm * 128 + fm * 16 + r4 + r) * N + (n0 + wn * 64 + fn * 16 + qi)] =
              acc[fm][fn][r];
  }
}

// ---------------------------------------------------------------------------
// RoPE + splitK-sum + scatter. Round-11: Q is pre-scaled by SCL_LOG2 (f32,
// before bf16 pack) so attn's softmax skips the per-element scale. xk/xv
// outputs unscaled (unchanged).
// ---------------------------------------------------------------------------
__global__ __launch_bounds__(256) void rope_scatter(
    const unsigned short* __restrict__ qkvp, const float* __restrict__ fr,
    const float* __restrict__ fi,
    unsigned short* __restrict__ qb, unsigned short* __restrict__ kb,
    unsigned short* __restrict__ vbuf, float* __restrict__ xk, float* __restrict__ xv) {
  const int idx = blockIdx.x * 256 + threadIdx.x;
  const int token = idx / 3072;
  const int col2  = (idx - token * 3072) * 2;
  const int pos   = token & 2047;
  const unsigned u1 = *(const unsigned*)(qkvp + (size_t)token * 6144 + col2);
  const unsigned u2 = *(const unsigned*)(qkvp + 25165824u + (size_t)token * 6144 + col2);
  float v0 = b2f((unsigned short)u1) + b2f((unsigned short)u2);
  float v1 = b2f((unsigned short)(u1 >> 16)) + b2f((unsigned short)(u2 >> 16));
  if (col2 < 4096) {
    const int j = (col2 & 127) >> 1;
    const float cr = fr[pos * 64 + j], ci = fi[pos * 64 + j];
    const float a = (v0 * cr - ci * v1) * SCL_LOG2;
    const float o = (v0 * ci + v1 * cr) * SCL_LOG2;
    *(unsigned*)(qb + (size_t)token * 4096 + col2) = pk2(a, o);
  } else if (col2 < 5120) {
    const int lc = col2 - 4096;
    const int j = (lc & 127) >> 1;
    const float cr = fr[pos * 64 + j], ci = fi[pos * 64 + j];
    const float a = v0 * cr - ci * v1;
    const float o = v0 * ci + v1 * cr;
    *(unsigned*)(kb + (size_t)token * 1024 + lc) = pk2(a, o);
    f2v w; w.x = a; w.y = o;
    *(f2v*)(xk + (size_t)token * 1024 + lc) = w;
  } else {
    const int lc = col2 - 5120;
    *(unsigned*)(vbuf + (size_t)token * 1024 + lc) = pk2(v0, v1);
    f2v w; w.x = v0; w.y = v1;
    *(f2v*)(xv + (size_t)token * 1024 + lc) = w;
  }
}

// ---------------------------------------------------------------------------
// Causal GQA flash attention — 8 waves x 32 q-rows, 32x32x16 MFMA, KVBLK=64.
// Round-11: K double-buffered too (LDS 64K). Per tile t: QK reads Kbuf[t&1];
// BAR; stage K(t+2)->Kbuf[t&1], V(t+1)->Vbuf[(t+1)&1]; vmcnt(4) drains
// exactly {K(t+1),V(t)} — both issued ONE FULL ITERATION earlier (was: K
// gated at zero slack -> per-tile latency convoy). FIFO invariant: 4
// outstanding entering each iter, 8 after stage, drain 4. Q pre-scaled.
// ---------------------------------------------------------------------------
__global__ __launch_bounds__(512, 2) void attn_fwd(
    const unsigned short* __restrict__ qb, const unsigned short* __restrict__ kb,
    const unsigned short* __restrict__ vb, unsigned short* __restrict__ ao) {
  __shared__ __align__(16) char smem[65536];   // K dbuf 2x16K | V dbuf 2x16K; epi 32K reuse
  const int tid = threadIdx.x, lane = tid & 63, wv = tid >> 6;
  const int q31 = lane & 31, hi = lane >> 5;
  const int qtb = 7 - blockIdx.x;              // long blocks launch first
  const int h = blockIdx.y, b = blockIdx.z, kvh = h >> 2;
  const int q0 = qtb * 256;
  const int qrow = q0 + wv * 32 + q31;

  s8v qf[8];
  {
    const unsigned short* qp = qb + (size_t)(b * 2048 + qrow) * 4096 + h * 128 + hi * 8;
#pragma unroll
    for (int c = 0; c < 8; ++c) qf[c] = *(const s8v*)(qp + c * 16);
  }

  f16v oacc[4];
#pragma unroll
  for (int i = 0; i < 4; ++i) oacc[i] = (f16v)0.0f;
  float m_run = -3.0e38f, l_run = 0.0f;

  const unsigned short* ksrc[2]; int kdo[2];
#pragma unroll
  for (int j = 0; j < 2; ++j) {
    const int r = wv * 8 + j * 4 + (lane >> 4);
    ksrc[j] = kb + (size_t)(b * 2048 + r) * 1024 + kvh * 128 + (((lane & 15) ^ (r & 15)) << 3);
    kdo[j] = (wv * 8 + j * 4) * 256;
  }
  const unsigned short* vsrc[2]; int vdo[2];
#pragma unroll
  for (int j = 0; j < 2; ++j) {
    const int key = (wv * 2 + j) * 4 + ((lane & 7) >> 1);
    const int d = ((lane >> 3) & 7) * 16 + (lane & 1) * 8;
    vsrc[j] = vb + (size_t)(b * 2048 + key) * 1024 + kvh * 128 + d;
    vdo[j] = (wv * 16 + j * 8) * 128;
  }

  const int ntiles = 4 * qtb + 4;
  const int my_qmax = q0 + wv * 32 + 31, wq_lo = q0 + wv * 32;

  // prologue: K0->Kbuf0, K1->Kbuf1, V0->Vbuf0 (6 loads); drain K0, leave 4
  GLDS16(ksrc[0], smem + kdo[0]);
  GLDS16(ksrc[1], smem + kdo[1]);
  GLDS16(ksrc[0] + 65536, smem + 16384 + kdo[0]);
  GLDS16(ksrc[1] + 65536, smem + 16384 + kdo[1]);
  GLDS16(vsrc[0], smem + 32768 + vdo[0]);
  GLDS16(vsrc[1], smem + 32768 + vdo[1]);
  asm volatile("s_waitcnt vmcnt(4)" ::: "memory");
  __builtin_amdgcn_sched_barrier(0);
  BAR;

  for (int t = 0; t < ntiles; ++t) {
    const int k0 = t * 64;
    const bool live = (k0 <= my_qmax);
    const char* Kbase = smem + (t & 1) * 16384;
    f16v s32a = (f16v)0.0f, s32b = (f16v)0.0f;
    if (live) {
      __builtin_amdgcn_s_setprio(1);
#pragma unroll
      for (int c = 0; c < 8; ++c) {
        const int sl = ((2 * c + hi) ^ (q31 & 15)) << 4;
        s8v kfa = *(const s8v*)(Kbase + q31 * 256 + sl);
        s8v kfb = *(const s8v*)(Kbase + (32 + q31) * 256 + sl);
        mfma3216(s32a, kfa, qf[c]);
        mfma3216(s32b, kfb, qf[c]);
      }
      __builtin_amdgcn_s_setprio(0);
      asm volatile("s_nop 7\n\ts_nop 7\n\ts_nop 7" : "+v"(s32a), "+v"(s32b));
    }
    BAR;                                       // all waves done: QK(t) reads, PV(t-1) reads
    {
      const int kt2 = (t + 2 < ntiles) ? t + 2 : ntiles - 1;   // clamped: dead dest
      const int vt1 = (t + 1 < ntiles) ? t + 1 : ntiles - 1;
      char* kd = smem + (t & 1) * 16384;                       // Kbuf[(t+2)&1]
      char* vd = smem + 32768 + ((t + 1) & 1) * 16384;         // Vbuf[(t+1)&1]
      GLDS16(ksrc[0] + (size_t)kt2 * 65536, kd + kdo[0]);
      GLDS16(ksrc[1] + (size_t)kt2 * 65536, kd + kdo[1]);
      GLDS16(vsrc[0] + (size_t)vt1 * 65536, vd + vdo[0]);
      GLDS16(vsrc[1] + (size_t)vt1 * 65536, vd + vdo[1]);
    }
    asm volatile("s_waitcnt vmcnt(4)" ::: "memory");  // drains K(t+1)+V(t): 1 iter slack
    __builtin_amdgcn_sched_barrier(0);
    BAR;
    if (live) {
      const char* vbt = smem + 32768 + (t & 1) * 16384 + hi * 2048 +
                        ((lane >> 4) & 1) * 128 + ((lane & 15) << 3);
      s4v tA[8], tB[8];
#pragma unroll
      for (int u = 0; u < 8; ++u) tA[u] = tr_read(vbt, (u >> 1) * 256 + (u & 1) * 1024);

      float p[32];
#pragma unroll
      for (int r = 0; r < 16; ++r) { p[r] = s32a[r]; p[16 + r] = s32b[r]; }
      float tm = -3.0e38f;
      if (k0 + 64 <= wq_lo) {                  // fully unmasked (Q pre-scaled: no mul)
#pragma unroll
        for (int j = 0; j < 32; ++j) tm = fmaxf(tm, p[j]);
      } else {
#pragma unroll
        for (int j = 0; j < 32; ++j) {
          const int keyg = k0 + (j >> 4) * 32 + (j & 3) + 8 * ((j >> 2) & 3) + 4 * hi;
          p[j] = (keyg <= qrow) ? p[j] : -3.0e38f;
          tm = fmaxf(tm, p[j]);
        }
      }
      tm = fmaxf(tm, __shfl_xor(tm, 32));

      if (!__all(tm - m_run <= 8.0f)) {        // T13 defer-max
        const float m_new = fmaxf(m_run, tm);
        const float al = exp2f(m_run - m_new);
#pragma unroll
        for (int i = 0; i < 4; ++i)
#pragma unroll
          for (int r = 0; r < 16; ++r) oacc[i][r] *= al;
        l_run *= al;
        m_run = m_new;
      }
      float ps = 0.0f;
#pragma unroll
      for (int j = 0; j < 32; ++j) { p[j] = exp2f(p[j] - m_run); ps += p[j]; }
      ps += __shfl_xor(ps, 32);
      l_run += ps;

      s8v pf[4];
#pragma unroll
      for (int ks = 0; ks < 4; ++ks) {
        unsigned c0, c1, c2, c3;
        asm("v_cvt_pk_bf16_f32 %0, %1, %2" : "=v"(c0) : "v"(p[ks*8+0]), "v"(p[ks*8+1]));
        asm("v_cvt_pk_bf16_f32 %0, %1, %2" : "=v"(c1) : "v"(p[ks*8+2]), "v"(p[ks*8+3]));
        asm("v_cvt_pk_bf16_f32 %0, %1, %2" : "=v"(c2) : "v"(p[ks*8+4]), "v"(p[ks*8+5]));
        asm("v_cvt_pk_bf16_f32 %0, %1, %2" : "=v"(c3) : "v"(p[ks*8+6]), "v"(p[ks*8+7]));
        asm volatile("v_permlane32_swap_b32 %0, %1" : "+v"(c0), "+v"(c2));
        asm volatile("v_permlane32_swap_b32 %0, %1" : "+v"(c1), "+v"(c3));
        u4v pw; pw.x = c0; pw.y = c1; pw.z = c2; pw.w = c3;
        pf[ks] = __builtin_bit_cast(s8v, pw);
      }

#define PVS(KS, CUR, NXT, LAST) do { \
        if (!(LAST)) { \
          _Pragma("unroll") for (int u = 0; u < 8; ++u) \
            NXT[u] = tr_read(vbt, ((KS)+1)*4096 + (u >> 1) * 256 + (u & 1) * 1024); \
          asm volatile("s_waitcnt lgkmcnt(8)" ::: "memory"); \
        } else { asm volatile("s_waitcnt lgkmcnt(0)" ::: "memory"); } \
        __builtin_amdgcn_sched_barrier(0); \
        __builtin_amdgcn_s_setprio(1); \
        _Pragma("unroll") for (int dt = 0; dt < 4; ++dt) { \
          s8v vf = __builtin_shufflevector(CUR[dt*2], CUR[dt*2+1], 0,1,2,3,4,5,6,7); \
          mfma3216(oacc[dt], vf, pf[KS]); } \
        __builtin_amdgcn_s_setprio(0); \
      } while (0)
      PVS(0, tA, tB, 0);
      PVS(1, tB, tA, 0);
      PVS(2, tA, tB, 0);
      PVS(3, tB, tA, 1);
#undef PVS
    }
  }

  asm volatile("s_waitcnt vmcnt(0) lgkmcnt(0)" ::: "memory");
  asm volatile("s_nop 7\n\ts_nop 7\n\ts_nop 7" ::: "memory");
  __syncthreads();
  const float inv = 1.0f / l_run;
  float* Ost = (float*)smem;
  const int er = tid >> 3, ew = (tid & 7) * 16;
#pragma unroll
  for (int pq = 0; pq < 4; ++pq) {
    if ((wv >> 1) == pq) {
      const int qip = (wv & 1) * 32 + q31;
#pragma unroll
      for (int dt = 0; dt < 4; ++dt)
#pragma unroll
        for (int r = 0; r < 16; ++r) {
          const int d = dt * 32 + (r & 3) + 8 * ((r >> 2) & 3) + 4 * hi;
          Ost[qip * 128 + (d ^ ((qip & 7) << 2))] = oacc[dt][r] * inv;
        }
    }
    __syncthreads();
    const int sw = (er & 7) << 2;
    f4v a0 = *(const f4v*)(Ost + er * 128 + ((ew + 0) ^ sw));
    f4v a1 = *(const f4v*)(Ost + er * 128 + ((ew + 4) ^ sw));
    f4v a2 = *(const f4v*)(Ost + er * 128 + ((ew + 8) ^ sw));
    f4v a3 = *(const f4v*)(Ost + er * 128 + ((ew + 12) ^ sw));
    u4v r0, r1;
    r0.x = pk2(a0[0], a0[1]); r0.y = pk2(a0[2], a0[3]);
    r0.z = pk2(a1[0], a1[1]); r0.w = pk2(a1[2], a1[3]);
    r1.x = pk2(a2[0], a2[1]); r1.y = pk2(a2[2], a2[3]);
    r1.z = pk2(a3[0], a3[1]); r1.w = pk2(a3[2], a3[3]);
    unsigned short* dst = ao + (size_t)(b * 2048 + q0 + pq * 64 + er) * 4096 + h * 128 + ew;
    *(u4v*)dst = r0;
    *(u4v*)(dst + 8) = r1;
    __syncthreads();
  }
}

// ---------------------------------------------------------------------------
// Host launcher. Workspace layout (needs ws_size >= 268,435,456 B):
//   [0,32M)     xb bf16        [32M,80M)   wqkv bf16
//   [80M,112M)  wo bf16        [112M,208M) qkv bf16 partials C1|C2 (2x48M)
//                              (reused as attn_out bf16 after rope)
//   [208M,240M) q bf16         [240M,248M) k bf16    [248M,256M) v bf16
// ---------------------------------------------------------------------------
extern "C" void kernel_launch(void* const* d_in, const int* in_sizes, int n_in,
                              void* d_out, int out_size, void* d_ws, size_t ws_size,
                              hipStream_t stream) {
  (void)in_sizes; (void)n_in; (void)out_size; (void)ws_size;
  const float* x  = (const float*)d_in[0];
  const float* wq = (const float*)d_in[1];
  const float* wk = (const float*)d_in[2];
  const float* wv = (const float*)d_in[3];
  const float* wo = (const float*)d_in[4];
  const float* fr = (const float*)d_in[5];
  const float* fi = (const float*)d_in[6];

  float* out = (float*)d_out;
  float* xk  = out + 16777216;
  float* xv  = xk + 4194304;

  char* ws = (char*)d_ws;
  unsigned short* xb    = (unsigned short*)(ws);
  unsigned short* wqkvb = (unsigned short*)(ws + 33554432);
  unsigned short* wob   = (unsigned short*)(ws + 83886080);
  unsigned short* qkvb  = (unsigned short*)(ws + 117440512);  // C1|C2 bf16
  unsigned short* aob   = (unsigned short*)(ws + 117440512);  // reuse after rope
  unsigned short* qbuf  = (unsigned short*)(ws + 218103808);
  unsigned short* kbuf  = (unsigned short*)(ws + 251658240);
  unsigned short* vbuf  = (unsigned short*)(ws + 260046848);

  cvt_bf16<<<16384, 256, 0, stream>>>(x,  xb, 4194304);
  cvt_bf16<<<16384, 256, 0, stream>>>(wq, wqkvb, 4194304);
  cvt_bf16<<<4096,  256, 0, stream>>>(wk, wqkvb + 16777216, 1048576);
  cvt_bf16<<<4096,  256, 0, stream>>>(wv, wqkvb + 20971520, 1048576);
  cvt_bf16<<<16384, 256, 0, stream>>>(wo, wob, 4194304);

  // qkv: splitK (K halves of 2048), 768 blocks = 3 exact rounds on 256 CUs
  gemm_bt8<1><<<768, 512, 0, stream>>>(xb, wqkvb, qkvb, 4096, 6144, 4096, 2048, 384);
  rope_scatter<<<49152, 256, 0, stream>>>(qkvb, fr, fi, qbuf, kbuf, vbuf, xk, xv);
  attn_fwd<<<dim3(8, 32, 2), 512, 0, stream>>>(qbuf, kbuf, vbuf, aob);
  gemm_bt8<0><<<256, 512, 0, stream>>>(aob, wob, out, 4096, 4096, 4096, 4096, 256);
}